// Round 11
// baseline (479.575 us; speedup 1.0000x reference)
//
#include <hip/hip_runtime.h>
#include <math.h>

#define NWAVE   8
#define NATOMS  16384
#define NPAIRS  524288
#define NSPEC   117
#define TBLN    (NSPEC * NSPEC)
#define NPADC   (NPAIRS + NATOMS * 8)   // 655360 max padded slots
#define CBLK    (NATOMS / 4)
#define TBLK    ((TBLN + 3) / 4)

typedef unsigned short ushort_t;
typedef unsigned int uint_t;

// ---------- helpers ----------
__device__ __forceinline__ float wred_sum(float v) {
#pragma unroll
    for (int o = 1; o < 64; o <<= 1) v += __shfl_xor(v, o, 64);
    return v;
}

__device__ __forceinline__ float ln_silu(float h, float gg, float bb) {
    float m = wred_sum(h) * (1.f / 64.f);
    float c = h - m;
    float v = wred_sum(c * c) * (1.f / 64.f);
    float y = c * rsqrtf(v + 1e-5f) * gg + bb;
    return y / (1.f + expf(-y));
}

__device__ __forceinline__ float dot4(float4 a, float4 b) {
    return a.x * b.x + a.y * b.y + a.z * b.z + a.w * b.w;
}

__device__ __forceinline__ ushort_t f2bf(float x) {
    uint_t u = __float_as_uint(x);
    u += 0x7FFF + ((u >> 16) & 1);
    return (ushort_t)(u >> 16);
}
__device__ __forceinline__ float bf2f(ushort_t s) {
    return __uint_as_float(((uint_t)s) << 16);
}

// ---------- k_hist: histogram + dist_vec output + plist init ----------
__global__ void k_hist(const int* __restrict__ aidx, const float* __restrict__ cart,
                       int* __restrict__ cnt, int* __restrict__ plist,
                       float* __restrict__ dist_out) {
    int p = blockIdx.x * 256 + threadIdx.x;
    if (p < NPAIRS) {
        atomicAdd(&cnt[aidx[p]], 1);
        int i0 = aidx[p];
        int i1 = aidx[NPAIRS + p];
        float dv0 = cart[i0 * 3 + 0] - cart[i1 * 3 + 0];
        float dv1 = cart[i0 * 3 + 1] - cart[i1 * 3 + 1];
        float dv2 = cart[i0 * 3 + 2] - cart[i1 * 3 + 2];
        dist_out[(size_t)p * 3 + 0] = dv0;
        dist_out[(size_t)p * 3 + 1] = dv1;
        dist_out[(size_t)p * 3 + 2] = dv2;
    }
    for (int q = p; q < NPADC; q += NPAIRS) plist[q] = -1;
}

__global__ void k_scan(const int* __restrict__ cnt, int* __restrict__ offs,
                       int* __restrict__ cursor) {
    __shared__ int sums[1024];
    int t = threadIdx.x;
    int base = t * 16;
    int v[16];
    int s = 0;
#pragma unroll
    for (int u = 0; u < 16; u++) { v[u] = (cnt[base + u] + 7) & ~7; s += v[u]; }
    sums[t] = s;
    __syncthreads();
    for (int d = 1; d < 1024; d <<= 1) {
        int x = (t >= d) ? sums[t - d] : 0;
        __syncthreads();
        sums[t] += x;
        __syncthreads();
    }
    int run = (t == 0) ? 0 : sums[t - 1];
#pragma unroll
    for (int u = 0; u < 16; u++) {
        offs[base + u] = run;
        cursor[base + u] = run;
        run += v[u];
    }
    if (t == 1023) offs[NATOMS] = run;
}

__global__ void k_scatter(const int* __restrict__ ai0, int* __restrict__ cursor,
                          int* __restrict__ plist) {
    int p = blockIdx.x * 256 + threadIdx.x;
    if (p < NPAIRS) {
        int pos = atomicAdd(&cursor[ai0[p]], 1);
        plist[pos] = p;
    }
}

// ---------- k_emb: center MLP + table MLP, one kernel ----------
__global__ void k_emb(const int* __restrict__ spec,
                      const float* __restrict__ cW1, const float* __restrict__ cb1,
                      const float* __restrict__ cg,  const float* __restrict__ cbe,
                      const float* __restrict__ cW2, const float* __restrict__ cb2,
                      float* __restrict__ ccoef,
                      const float* __restrict__ nW1, const float* __restrict__ nb1,
                      const float* __restrict__ ng,  const float* __restrict__ nbe,
                      const float* __restrict__ nW2, const float* __restrict__ nb2,
                      float* __restrict__ table) {
    __shared__ float h_s[4][64];
    int lane = threadIdx.x & 63, slot = threadIdx.x >> 6;
    if (blockIdx.x < CBLK) {
        int atom = blockIdx.x * 4 + slot;
        int s = spec[atom] + 1;
        float h = cW1[s * 64 + lane] + cb1[lane];
        h = ln_silu(h, cg[lane], cbe[lane]);
        h_s[slot][lane] = h;
        __syncthreads();
        float o = cb2[lane];
#pragma unroll 8
        for (int i = 0; i < 64; i++) o += h_s[slot][i] * cW2[i * 64 + lane];
        ccoef[atom * 64 + lane] = o;
    } else {
        int key = (blockIdx.x - CBLK) * 4 + slot;
        int kk = (key < TBLN) ? key : 0;
        int s0 = kk / NSPEC + 1, s1 = kk % NSPEC + 1;
        float h = nW1[s0 * 64 + lane] + nW1[s1 * 64 + lane] + nb1[lane];
        h = ln_silu(h, ng[lane], nbe[lane]);
        h_s[slot][lane] = h;
        __syncthreads();
        if (lane < 24 && key < TBLN) {
            float o = nb2[lane];
#pragma unroll 8
            for (int i = 0; i < 64; i++) o += h_s[slot][i] * nW2[i * 24 + lane];
            table[key * 24 + lane] = o;
        }
    }
}

// ---------- per-pair: planar bf16 streams ----------
__global__ void k_pair2(const float* __restrict__ cart, const int* __restrict__ aidx,
                        const int* __restrict__ spec,  const float* __restrict__ table,
                        const int* __restrict__ plist, const int* __restrict__ total_p,
                        ushort_t* __restrict__ ang16,  ushort_t* __restrict__ rad16,
                        int* __restrict__ keyv,        int* __restrict__ neigh) {
    int pos = blockIdx.x * 256 + threadIdx.x;
    if (pos >= total_p[0]) return;
    int p = plist[pos];
    if (p < 0) {
#pragma unroll
        for (int j = 0; j < 4; j++) ang16[(size_t)j * NPADC + pos] = 0;
#pragma unroll
        for (int k = 0; k < 8; k++) rad16[(size_t)k * NPADC + pos] = 0;
        keyv[pos] = 0;
        neigh[pos] = 0;
        return;
    }
    int i0 = aidx[p];
    int i1 = aidx[NPAIRS + p];
    float dv0 = cart[i0 * 3 + 0] - cart[i1 * 3 + 0];
    float dv1 = cart[i0 * 3 + 1] - cart[i1 * 3 + 1];
    float dv2 = cart[i0 * 3 + 2] - cart[i1 * 3 + 2];
    float d = sqrtf(dv0 * dv0 + dv1 * dv1 + dv2 * dv2);

    int key = spec[i0] * NSPEC + spec[i1];
    const float4* ne = (const float4*)(table + (size_t)key * 24);
    float4 al_a = ne[2], al_b = ne[3];
    float4 mu_a = ne[4], mu_b = ne[5];

    float cth = cosf(d * (float)(M_PI / 4.0));
    float t0 = 0.5f * cth + 0.5f;
    float fc = t0 * t0;
    ang16[(size_t)0 * NPADC + pos] = f2bf(fc);
    ang16[(size_t)1 * NPADC + pos] = f2bf(dv0 * fc);
    ang16[(size_t)2 * NPADC + pos] = f2bf(dv1 * fc);
    ang16[(size_t)3 * NPADC + pos] = f2bf(dv2 * fc);

    float r[8];
    float t;
    t = al_a.x * (d - mu_a.x); r[0] = expf(-t * t);
    t = al_a.y * (d - mu_a.y); r[1] = expf(-t * t);
    t = al_a.z * (d - mu_a.z); r[2] = expf(-t * t);
    t = al_a.w * (d - mu_a.w); r[3] = expf(-t * t);
    t = al_b.x * (d - mu_b.x); r[4] = expf(-t * t);
    t = al_b.y * (d - mu_b.y); r[5] = expf(-t * t);
    t = al_b.z * (d - mu_b.z); r[6] = expf(-t * t);
    t = al_b.w * (d - mu_b.w); r[7] = expf(-t * t);
#pragma unroll
    for (int k = 0; k < 8; k++) rad16[(size_t)k * NPADC + pos] = f2bf(r[k]);
    keyv[pos] = key;
    neigh[pos] = i1;
}

// ---------- fused pass: R10 gather shape + in-kernel MLP, 8 atoms/block ----------
template <bool PASS0, bool FINAL>
__global__ __launch_bounds__(256, 6)
void k_pass(const int* __restrict__ offs,
            const ushort_t* __restrict__ ang16, const ushort_t* __restrict__ rad16,
            const int* __restrict__ keyv,  const float* __restrict__ table,
            const int* __restrict__ neigh, const float* __restrict__ S_in,
            float* __restrict__ co0,       const float* __restrict__ ccenter,
            const float* __restrict__ cc_g,
            const float* __restrict__ W1,  const float* __restrict__ b1,
            const float* __restrict__ g,   const float* __restrict__ be,
            const float* __restrict__ W2,  const float* __restrict__ b2,
            const int* __restrict__ spec,  float* __restrict__ dst) {
    __shared__ float w1_s[4096];     // raw [i][o]
    __shared__ float cc_s[1024];     // raw [row][k][m]
    __shared__ float w2t_s[512];     // [o][i] (oc); first 64 = W2 vec (final)
    __shared__ float b1_s[64], g_s[64], be_s[64], b2_s[8];
    __shared__ float co_s[8][32];
    __shared__ float dens_s[4][64], h_s[4][64];

    const int t = threadIdx.x, lane = t & 63, wv = t >> 6;
    const int abase = blockIdx.x * 8;

    // ---- stage weights (L2-hot) ----
    for (int i = t; i < 1024; i += 256) ((float4*)w1_s)[i] = ((const float4*)W1)[i];
    if (t < 256) ((float4*)cc_s)[t] = ((const float4*)cc_g)[t];
    if (FINAL) {
        if (t < 64) w2t_s[t] = W2[t];
        if (t == 64) b2_s[0] = b2[0];
    } else {
        if (t < 256) {  // transpose W2 (64x8) -> w2t (8x64)
            int i = t >> 2, o0 = (t & 3) * 2;
            w2t_s[(o0 + 0) * 64 + i] = W2[i * 8 + o0 + 0];
            w2t_s[(o0 + 1) * 64 + i] = W2[i * 8 + o0 + 1];
        }
        if (t >= 256 - 8) b2_s[t - 248] = b2[t - 248];
    }
    if (t < 64) { b1_s[t] = b1[t]; g_s[t] = g[t]; be_s[t] = be[t]; }

    // ---- gather (R10 shape): half-wave per atom ----
    {
        int la = wv * 2 + (lane >> 5);            // 0..7
        int atom = abase + la;
        int start = offs[atom], end = offs[atom + 1];
        int jk = lane & 31, j = jk >> 3, k = jk & 7;
        const ushort_t* aj = ang16 + (size_t)j * NPADC + start;
        const ushort_t* rk = rad16 + (size_t)k * NPADC + start;
        float acc = 0.f;
        if (PASS0) {
            const int* kb = keyv + start;
            for (int q = 0; q < end - start; q += 8) {
                ushort4 a0 = *(const ushort4*)(aj + q), a1 = *(const ushort4*)(aj + q + 4);
                ushort4 r0 = *(const ushort4*)(rk + q), r1 = *(const ushort4*)(rk + q + 4);
                int4 k0 = *(const int4*)(kb + q), k1 = *(const int4*)(kb + q + 4);
                float w0 = table[(size_t)k0.x * 24 + k];
                float w1v = table[(size_t)k0.y * 24 + k];
                float w2v = table[(size_t)k0.z * 24 + k];
                float w3 = table[(size_t)k0.w * 24 + k];
                float w4 = table[(size_t)k1.x * 24 + k];
                float w5 = table[(size_t)k1.y * 24 + k];
                float w6 = table[(size_t)k1.z * 24 + k];
                float w7 = table[(size_t)k1.w * 24 + k];
                acc += bf2f(a0.x) * bf2f(r0.x) * w0 + bf2f(a0.y) * bf2f(r0.y) * w1v
                     + bf2f(a0.z) * bf2f(r0.z) * w2v + bf2f(a0.w) * bf2f(r0.w) * w3
                     + bf2f(a1.x) * bf2f(r1.x) * w4 + bf2f(a1.y) * bf2f(r1.y) * w5
                     + bf2f(a1.z) * bf2f(r1.z) * w6 + bf2f(a1.w) * bf2f(r1.w) * w7;
            }
            co0[(size_t)atom * 32 + jk] = acc;
            co_s[la][jk] = acc;
        } else {
            const int* nbp = neigh + start;
            for (int q = 0; q < end - start; q += 8) {
                ushort4 a0 = *(const ushort4*)(aj + q), a1 = *(const ushort4*)(aj + q + 4);
                ushort4 r0 = *(const ushort4*)(rk + q), r1 = *(const ushort4*)(rk + q + 4);
                int4 n0 = *(const int4*)(nbp + q), n1 = *(const int4*)(nbp + q + 4);
                float w0 = S_in[(size_t)n0.x * 8 + k];
                float w1v = S_in[(size_t)n0.y * 8 + k];
                float w2v = S_in[(size_t)n0.z * 8 + k];
                float w3 = S_in[(size_t)n0.w * 8 + k];
                float w4 = S_in[(size_t)n1.x * 8 + k];
                float w5 = S_in[(size_t)n1.y * 8 + k];
                float w6 = S_in[(size_t)n1.z * 8 + k];
                float w7 = S_in[(size_t)n1.w * 8 + k];
                acc += bf2f(a0.x) * bf2f(r0.x) * w0 + bf2f(a0.y) * bf2f(r0.y) * w1v
                     + bf2f(a0.z) * bf2f(r0.z) * w2v + bf2f(a0.w) * bf2f(r0.w) * w3
                     + bf2f(a1.x) * bf2f(r1.x) * w4 + bf2f(a1.y) * bf2f(r1.y) * w5
                     + bf2f(a1.z) * bf2f(r1.z) * w6 + bf2f(a1.w) * bf2f(r1.w) * w7;
            }
            co_s[la][jk] = acc + co0[(size_t)atom * 32 + jk];
        }
    }
    __syncthreads();   // co_s + staged weights ready

    // ---- contraction + MLP: wave wv handles local atoms wv, wv+4 ----
#pragma unroll 1
    for (int la = wv; la < 8; la += 4) {
        int atom = abase + la;
        float dens = ccenter[(size_t)atom * 64 + lane];
        {
            float s = 0.f;
#pragma unroll
            for (int kk = 0; kk < 8; kk++) s += co_s[la][kk] * cc_s[kk * 64 + lane];
            dens += s * s;
        }
#pragma unroll
        for (int jj = 1; jj < 4; jj++) {
            float s = 0.f;
#pragma unroll
            for (int kk = 0; kk < 8; kk++)
                s += co_s[la][jj * 8 + kk] * cc_s[512 + kk * 64 + lane];
            dens += s * s;
        }
        dens_s[wv][lane] = dens;   // wave-private row

        float h = b1_s[lane];
        const float4* dp = (const float4*)dens_s[wv];
#pragma unroll
        for (int q = 0; q < 16; q++) {
            float4 dv = dp[q];
            h += dv.x * w1_s[(q * 4 + 0) * 64 + lane]
               + dv.y * w1_s[(q * 4 + 1) * 64 + lane]
               + dv.z * w1_s[(q * 4 + 2) * 64 + lane]
               + dv.w * w1_s[(q * 4 + 3) * 64 + lane];
        }
        h = ln_silu(h, g_s[lane], be_s[lane]);

        if (FINAL) {
            float s = wred_sum(h * w2t_s[lane]);
            if (lane == 0) {
                float mask = (spec[atom] >= 0) ? 1.f : 0.f;
                dst[atom] = (s + b2_s[0]) * mask;
            }
        } else {
            h_s[wv][lane] = h;     // wave-private row
            int o = lane >> 3, seg = lane & 7;
            const float4* w2p = (const float4*)(w2t_s + o * 64 + seg * 8);
            const float4* hp  = (const float4*)(&h_s[wv][seg * 8]);
            float part = dot4(w2p[0], hp[0]) + dot4(w2p[1], hp[1]);
            part += __shfl_xor(part, 1, 64);
            part += __shfl_xor(part, 2, 64);
            part += __shfl_xor(part, 4, 64);
            if (seg == 0) {
                float val = part + b2_s[o];
                if (!PASS0) val += S_in[(size_t)atom * 8 + o];
                dst[(size_t)atom * 8 + o] = val;
            }
        }
    }
}

extern "C" void kernel_launch(void* const* d_in, const int* in_sizes, int n_in,
                              void* d_out, int out_size, void* d_ws, size_t ws_size,
                              hipStream_t stream) {
    const float* cart   = (const float*)d_in[0];
    const int*   aidx   = (const int*)d_in[1];
    const int*   spec   = (const int*)d_in[2];
    const float* ccoeff = (const float*)d_in[4];
    const float* embn_W1 = (const float*)d_in[5];
    const float* embn_b1 = (const float*)d_in[6];
    const float* embn_g  = (const float*)d_in[7];
    const float* embn_be = (const float*)d_in[8];
    const float* embn_W2 = (const float*)d_in[9];
    const float* embn_b2 = (const float*)d_in[10];
    const float* embc_W1 = (const float*)d_in[11];
    const float* embc_b1 = (const float*)d_in[12];
    const float* embc_g  = (const float*)d_in[13];
    const float* embc_be = (const float*)d_in[14];
    const float* embc_W2 = (const float*)d_in[15];
    const float* embc_b2 = (const float*)d_in[16];
    const float* oc_W1 = (const float*)d_in[17];
    const float* oc_b1 = (const float*)d_in[18];
    const float* oc_g  = (const float*)d_in[19];
    const float* oc_be = (const float*)d_in[20];
    const float* oc_W2 = (const float*)d_in[21];
    const float* oc_b2 = (const float*)d_in[22];
    const float* out_W1 = (const float*)d_in[23];
    const float* out_b1 = (const float*)d_in[24];
    const float* out_g  = (const float*)d_in[25];
    const float* out_be = (const float*)d_in[26];
    const float* out_W2 = (const float*)d_in[27];
    const float* out_b2 = (const float*)d_in[28];

    float* outp = (float*)d_out;

    char* ws = (char*)d_ws;
    size_t off = 0;
    auto carve = [&](size_t bytes) { size_t o = off; off = (off + bytes + 255) & ~(size_t)255; return o; };
    ushort_t* ang16 = (ushort_t*)(ws + carve((size_t)4 * NPADC * 2));
    ushort_t* rad16 = (ushort_t*)(ws + carve((size_t)8 * NPADC * 2));
    int*   keyv    = (int*)(ws + carve((size_t)NPADC * 4));
    int*   neigh   = (int*)(ws + carve((size_t)NPADC * 4));
    int*   plist   = (int*)(ws + carve((size_t)NPADC * 4));
    float* ccenter = (float*)(ws + carve((size_t)NATOMS * 64 * 4));
    float* co0     = (float*)(ws + carve((size_t)NATOMS * 32 * 4));
    float* Sa      = (float*)(ws + carve((size_t)NATOMS * 8 * 4));
    float* Sb      = (float*)(ws + carve((size_t)NATOMS * 8 * 4));
    float* table   = (float*)(ws + carve((size_t)TBLN * 24 * 4));
    int*   cnt     = (int*)(ws + carve((size_t)NATOMS * 4));
    int*   offs    = (int*)(ws + carve((size_t)(NATOMS + 1) * 4));
    int*   cursor  = (int*)(ws + carve((size_t)NATOMS * 4));

    hipMemsetAsync(cnt, 0, (size_t)NATOMS * 4, stream);
    k_hist<<<NPAIRS / 256, 256, 0, stream>>>(aidx, cart, cnt, plist, outp);
    k_scan<<<1, 1024, 0, stream>>>(cnt, offs, cursor);
    k_scatter<<<NPAIRS / 256, 256, 0, stream>>>(aidx, cursor, plist);

    k_emb<<<CBLK + TBLK, 256, 0, stream>>>(spec,
                                           embc_W1, embc_b1, embc_g, embc_be, embc_W2, embc_b2,
                                           ccenter,
                                           embn_W1, embn_b1, embn_g, embn_be, embn_W2, embn_b2,
                                           table);

    k_pair2<<<NPADC / 256, 256, 0, stream>>>(cart, aidx, spec, table, plist, offs + NATOMS,
                                             ang16, rad16, keyv, neigh);

    // pass 0: co0 + oc0 -> Sa
    k_pass<true, false><<<NATOMS / 8, 256, 0, stream>>>(
        offs, ang16, rad16, keyv, table, neigh, nullptr, co0, ccenter,
        ccoeff + 0 * 1024, oc_W1 + 0 * 4096, oc_b1 + 0 * 64, oc_g + 0 * 64,
        oc_be + 0 * 64, oc_W2 + 0 * 512, oc_b2 + 0 * 8, spec, Sa);
    // pass 1: S=Sa -> Sb (= Sa + oc1)
    k_pass<false, false><<<NATOMS / 8, 256, 0, stream>>>(
        offs, ang16, rad16, keyv, table, neigh, Sa, co0, ccenter,
        ccoeff + 1 * 1024, oc_W1 + 1 * 4096, oc_b1 + 1 * 64, oc_g + 1 * 64,
        oc_be + 1 * 64, oc_W2 + 1 * 512, oc_b2 + 1 * 8, spec, Sb);
    // pass 2: S=Sb -> Sa (= Sb + oc2)
    k_pass<false, false><<<NATOMS / 8, 256, 0, stream>>>(
        offs, ang16, rad16, keyv, table, neigh, Sb, co0, ccenter,
        ccoeff + 2 * 1024, oc_W1 + 2 * 4096, oc_b1 + 2 * 64, oc_g + 2 * 64,
        oc_be + 2 * 64, oc_W2 + 2 * 512, oc_b2 + 2 * 8, spec, Sa);
    // final: S=Sa -> output
    k_pass<false, true><<<NATOMS / 8, 256, 0, stream>>>(
        offs, ang16, rad16, keyv, table, neigh, Sa, co0, ccenter,
        ccoeff + 3 * 1024, out_W1, out_b1, out_g, out_be,
        out_W2, out_b2, spec, outp + (size_t)NPAIRS * 3);
}

// Round 12
// 244.304 us; speedup vs baseline: 1.9630x; 1.9630x over previous
//
#include <hip/hip_runtime.h>
#include <math.h>

#define NWAVE   8
#define NATOMS  16384
#define NPAIRS  524288
#define NSPEC   117
#define TBLN    (NSPEC * NSPEC)
#define NPADC   (NPAIRS + NATOMS * 8)   // 655360 max padded slots
#define CBLK    (NATOMS / 4)
#define TBLK    ((TBLN + 3) / 4)
#define AMLP    32                      // atoms per block in k_mlp

typedef unsigned short ushort_t;
typedef unsigned int uint_t;

// ---------- helpers ----------
__device__ __forceinline__ float wred_sum(float v) {
#pragma unroll
    for (int o = 1; o < 64; o <<= 1) v += __shfl_xor(v, o, 64);
    return v;
}

__device__ __forceinline__ float ln_silu(float h, float gg, float bb) {
    float m = wred_sum(h) * (1.f / 64.f);
    float c = h - m;
    float v = wred_sum(c * c) * (1.f / 64.f);
    float y = c * rsqrtf(v + 1e-5f) * gg + bb;
    return y / (1.f + expf(-y));
}

__device__ __forceinline__ float dot4(float4 a, float4 b) {
    return a.x * b.x + a.y * b.y + a.z * b.z + a.w * b.w;
}

__device__ __forceinline__ ushort_t f2bf(float x) {
    uint_t u = __float_as_uint(x);
    u += 0x7FFF + ((u >> 16) & 1);
    return (ushort_t)(u >> 16);
}
__device__ __forceinline__ float bf2f(ushort_t s) {
    return __uint_as_float(((uint_t)s) << 16);
}

// ---------- k_hist: histogram + dist_vec output + plist init ----------
__global__ void k_hist(const int* __restrict__ aidx, const float* __restrict__ cart,
                       int* __restrict__ cnt, int* __restrict__ plist,
                       float* __restrict__ dist_out) {
    int p = blockIdx.x * 256 + threadIdx.x;
    if (p < NPAIRS) {
        atomicAdd(&cnt[aidx[p]], 1);
        int i0 = aidx[p];
        int i1 = aidx[NPAIRS + p];
        float dv0 = cart[i0 * 3 + 0] - cart[i1 * 3 + 0];
        float dv1 = cart[i0 * 3 + 1] - cart[i1 * 3 + 1];
        float dv2 = cart[i0 * 3 + 2] - cart[i1 * 3 + 2];
        dist_out[(size_t)p * 3 + 0] = dv0;
        dist_out[(size_t)p * 3 + 1] = dv1;
        dist_out[(size_t)p * 3 + 2] = dv2;
    }
    for (int q = p; q < NPADC; q += NPAIRS) plist[q] = -1;
}

__global__ void k_scan(const int* __restrict__ cnt, int* __restrict__ offs,
                       int* __restrict__ cursor) {
    __shared__ int sums[1024];
    int t = threadIdx.x;
    int base = t * 16;
    int v[16];
    int s = 0;
#pragma unroll
    for (int u = 0; u < 16; u++) { v[u] = (cnt[base + u] + 7) & ~7; s += v[u]; }
    sums[t] = s;
    __syncthreads();
    for (int d = 1; d < 1024; d <<= 1) {
        int x = (t >= d) ? sums[t - d] : 0;
        __syncthreads();
        sums[t] += x;
        __syncthreads();
    }
    int run = (t == 0) ? 0 : sums[t - 1];
#pragma unroll
    for (int u = 0; u < 16; u++) {
        offs[base + u] = run;
        cursor[base + u] = run;
        run += v[u];
    }
    if (t == 1023) offs[NATOMS] = run;
}

__global__ void k_scatter(const int* __restrict__ ai0, int* __restrict__ cursor,
                          int* __restrict__ plist) {
    int p = blockIdx.x * 256 + threadIdx.x;
    if (p < NPAIRS) {
        int pos = atomicAdd(&cursor[ai0[p]], 1);
        plist[pos] = p;
    }
}

// ---------- k_emb: center MLP + table MLP, one kernel ----------
__global__ void k_emb(const int* __restrict__ spec,
                      const float* __restrict__ cW1, const float* __restrict__ cb1,
                      const float* __restrict__ cg,  const float* __restrict__ cbe,
                      const float* __restrict__ cW2, const float* __restrict__ cb2,
                      float* __restrict__ ccoef,
                      const float* __restrict__ nW1, const float* __restrict__ nb1,
                      const float* __restrict__ ng,  const float* __restrict__ nbe,
                      const float* __restrict__ nW2, const float* __restrict__ nb2,
                      float* __restrict__ table) {
    __shared__ float h_s[4][64];
    int lane = threadIdx.x & 63, slot = threadIdx.x >> 6;
    if (blockIdx.x < CBLK) {
        int atom = blockIdx.x * 4 + slot;
        int s = spec[atom] + 1;
        float h = cW1[s * 64 + lane] + cb1[lane];
        h = ln_silu(h, cg[lane], cbe[lane]);
        h_s[slot][lane] = h;
        __syncthreads();
        float o = cb2[lane];
#pragma unroll 8
        for (int i = 0; i < 64; i++) o += h_s[slot][i] * cW2[i * 64 + lane];
        ccoef[atom * 64 + lane] = o;
    } else {
        int key = (blockIdx.x - CBLK) * 4 + slot;
        int kk = (key < TBLN) ? key : 0;
        int s0 = kk / NSPEC + 1, s1 = kk % NSPEC + 1;
        float h = nW1[s0 * 64 + lane] + nW1[s1 * 64 + lane] + nb1[lane];
        h = ln_silu(h, ng[lane], nbe[lane]);
        h_s[slot][lane] = h;
        __syncthreads();
        if (lane < 24 && key < TBLN) {
            float o = nb2[lane];
#pragma unroll 8
            for (int i = 0; i < 64; i++) o += h_s[slot][i] * nW2[i * 24 + lane];
            table[key * 24 + lane] = o;
        }
    }
}

// ---------- per-pair: planar bf16 streams, 2 pairs/thread ----------
__global__ void k_pair2(const float* __restrict__ cart, const int* __restrict__ aidx,
                        const int* __restrict__ spec,  const float* __restrict__ table,
                        const int* __restrict__ plist, const int* __restrict__ total_p,
                        ushort_t* __restrict__ ang16,  ushort_t* __restrict__ rad16,
                        int* __restrict__ keyv,        int* __restrict__ neigh) {
    int pos0 = (blockIdx.x * 256 + threadIdx.x) * 2;
    if (pos0 >= total_p[0]) return;   // total is a multiple of 8, so pos0+1 also valid
    int2 pp = *(const int2*)(plist + pos0);

    float angv[2][4];
    float radv[2][8];
    int keys[2], neis[2];
#pragma unroll
    for (int s = 0; s < 2; s++) {
        int p = s ? pp.y : pp.x;
        if (p < 0) {
#pragma unroll
            for (int j = 0; j < 4; j++) angv[s][j] = 0.f;
#pragma unroll
            for (int k = 0; k < 8; k++) radv[s][k] = 0.f;
            keys[s] = 0; neis[s] = 0;
            continue;
        }
        int i0 = aidx[p];
        int i1 = aidx[NPAIRS + p];
        float dv0 = cart[i0 * 3 + 0] - cart[i1 * 3 + 0];
        float dv1 = cart[i0 * 3 + 1] - cart[i1 * 3 + 1];
        float dv2 = cart[i0 * 3 + 2] - cart[i1 * 3 + 2];
        float d = sqrtf(dv0 * dv0 + dv1 * dv1 + dv2 * dv2);

        int key = spec[i0] * NSPEC + spec[i1];
        const float4* ne = (const float4*)(table + (size_t)key * 24);
        float4 al_a = ne[2], al_b = ne[3];
        float4 mu_a = ne[4], mu_b = ne[5];

        float cth = cosf(d * (float)(M_PI / 4.0));
        float t0 = 0.5f * cth + 0.5f;
        float fc = t0 * t0;
        angv[s][0] = fc; angv[s][1] = dv0 * fc; angv[s][2] = dv1 * fc; angv[s][3] = dv2 * fc;

        float t;
        t = al_a.x * (d - mu_a.x); radv[s][0] = expf(-t * t);
        t = al_a.y * (d - mu_a.y); radv[s][1] = expf(-t * t);
        t = al_a.z * (d - mu_a.z); radv[s][2] = expf(-t * t);
        t = al_a.w * (d - mu_a.w); radv[s][3] = expf(-t * t);
        t = al_b.x * (d - mu_b.x); radv[s][4] = expf(-t * t);
        t = al_b.y * (d - mu_b.y); radv[s][5] = expf(-t * t);
        t = al_b.z * (d - mu_b.z); radv[s][6] = expf(-t * t);
        t = al_b.w * (d - mu_b.w); radv[s][7] = expf(-t * t);
        keys[s] = key; neis[s] = i1;
    }
#pragma unroll
    for (int j = 0; j < 4; j++) {
        uint_t v = (uint_t)f2bf(angv[0][j]) | ((uint_t)f2bf(angv[1][j]) << 16);
        *(uint_t*)(ang16 + (size_t)j * NPADC + pos0) = v;
    }
#pragma unroll
    for (int k = 0; k < 8; k++) {
        uint_t v = (uint_t)f2bf(radv[0][k]) | ((uint_t)f2bf(radv[1][k]) << 16);
        *(uint_t*)(rad16 + (size_t)k * NPADC + pos0) = v;
    }
    *(int2*)(keyv + pos0) = make_int2(keys[0], keys[1]);
    *(int2*)(neigh + pos0) = make_int2(neis[0], neis[1]);
}

// ---------- gather kernel: half-wave per atom, software-pipelined chunks ----------
template <bool PASS0>
__global__ __launch_bounds__(256, 6)
void k_co(const int* __restrict__ offs,
          const ushort_t* __restrict__ ang16, const ushort_t* __restrict__ rad16,
          const int* __restrict__ keyv,  const float* __restrict__ table,
          const int* __restrict__ neigh, const float* __restrict__ S_in,
          const float* __restrict__ co0, float* __restrict__ co_out) {
    int lane = threadIdx.x & 63, wv = threadIdx.x >> 6;
    int la = wv * 2 + (lane >> 5);               // 0..7
    int atom = blockIdx.x * 8 + la;
    int start = offs[atom], end = offs[atom + 1];
    int n = end - start;                          // multiple of 8
    int jk = lane & 31, j = jk >> 3, k = jk & 7;
    const ushort_t* aj = ang16 + (size_t)j * NPADC + start;
    const ushort_t* rk = rad16 + (size_t)k * NPADC + start;
    const int* ib = (PASS0 ? keyv : neigh) + start;
    float acc = 0.f;

    ushort4 a0, a1, r0, r1;
    int4 i0, i1;
    if (n > 0) {
        a0 = *(const ushort4*)(aj);     a1 = *(const ushort4*)(aj + 4);
        r0 = *(const ushort4*)(rk);     r1 = *(const ushort4*)(rk + 4);
        i0 = *(const int4*)(ib);        i1 = *(const int4*)(ib + 4);
    }
    for (int q = 0; q < n; q += 8) {
        // issue the 8 scattered weight loads for the CURRENT chunk
        float w0, w1, w2, w3, w4, w5, w6, w7;
        if (PASS0) {
            w0 = table[(size_t)i0.x * 24 + k];
            w1 = table[(size_t)i0.y * 24 + k];
            w2 = table[(size_t)i0.z * 24 + k];
            w3 = table[(size_t)i0.w * 24 + k];
            w4 = table[(size_t)i1.x * 24 + k];
            w5 = table[(size_t)i1.y * 24 + k];
            w6 = table[(size_t)i1.z * 24 + k];
            w7 = table[(size_t)i1.w * 24 + k];
        } else {
            w0 = S_in[(size_t)i0.x * 8 + k];
            w1 = S_in[(size_t)i0.y * 8 + k];
            w2 = S_in[(size_t)i0.z * 8 + k];
            w3 = S_in[(size_t)i0.w * 8 + k];
            w4 = S_in[(size_t)i1.x * 8 + k];
            w5 = S_in[(size_t)i1.y * 8 + k];
            w6 = S_in[(size_t)i1.z * 8 + k];
            w7 = S_in[(size_t)i1.w * 8 + k];
        }
        // prefetch NEXT chunk's streams + indices (overlaps weight-load latency)
        ushort4 na0, na1, nr0, nr1;
        int4 ni0, ni1;
        if (q + 8 < n) {
            na0 = *(const ushort4*)(aj + q + 8);  na1 = *(const ushort4*)(aj + q + 12);
            nr0 = *(const ushort4*)(rk + q + 8);  nr1 = *(const ushort4*)(rk + q + 12);
            ni0 = *(const int4*)(ib + q + 8);     ni1 = *(const int4*)(ib + q + 12);
        }
        acc += bf2f(a0.x) * bf2f(r0.x) * w0 + bf2f(a0.y) * bf2f(r0.y) * w1
             + bf2f(a0.z) * bf2f(r0.z) * w2 + bf2f(a0.w) * bf2f(r0.w) * w3
             + bf2f(a1.x) * bf2f(r1.x) * w4 + bf2f(a1.y) * bf2f(r1.y) * w5
             + bf2f(a1.z) * bf2f(r1.z) * w6 + bf2f(a1.w) * bf2f(r1.w) * w7;
        a0 = na0; a1 = na1; r0 = nr0; r1 = nr1; i0 = ni0; i1 = ni1;
    }
    if (PASS0) {
        co_out[(size_t)atom * 32 + jk] = acc;
    } else {
        co_out[(size_t)atom * 32 + jk] = acc + co0[(size_t)atom * 32 + jk];
    }
}

// ---------- MLP kernel: contraction + MLP, weights LDS-staged, AMLP atoms/block ----------
template <bool PASS0, bool FINAL>
__global__ __launch_bounds__(256)
void k_mlp(const float* __restrict__ co, const float* __restrict__ ccenter,
           const float* __restrict__ cc_g,
           const float* __restrict__ W1, const float* __restrict__ b1,
           const float* __restrict__ g,  const float* __restrict__ be,
           const float* __restrict__ W2, const float* __restrict__ b2,
           const float* __restrict__ S_in, const int* __restrict__ spec,
           float* __restrict__ dst) {
    __shared__ float w1_s[4096];     // raw [i][o]
    __shared__ float cc_s[1024];     // raw [row][k][m]
    __shared__ float w2t_s[512];     // [o][i] (oc); first 64 = W2 vec (final)
    __shared__ float b1_s[64], g_s[64], be_s[64], b2_s[8];
    __shared__ float co_s[4][32], dens_s[4][64], h_s[4][64];

    const int t = threadIdx.x, lane = t & 63, wv = t >> 6;
    const int abase = blockIdx.x * AMLP;

    for (int i = t; i < 1024; i += 256) ((float4*)w1_s)[i] = ((const float4*)W1)[i];
    if (t < 256) ((float4*)cc_s)[t] = ((const float4*)cc_g)[t];
    if (FINAL) {
        if (t < 64) w2t_s[t] = W2[t];
        if (t == 64) b2_s[0] = b2[0];
    } else {
        if (t < 256) {  // transpose W2 (64x8) -> w2t (8x64)
            int i = t >> 2, o0 = (t & 3) * 2;
            w2t_s[(o0 + 0) * 64 + i] = W2[i * 8 + o0 + 0];
            w2t_s[(o0 + 1) * 64 + i] = W2[i * 8 + o0 + 1];
        }
        if (t >= 256 - 8) b2_s[t - 248] = b2[t - 248];
    }
    if (t < 64) { b1_s[t] = b1[t]; g_s[t] = g[t]; be_s[t] = be[t]; }
    __syncthreads();

#pragma unroll 1
    for (int la = wv; la < AMLP; la += 4) {
        int atom = abase + la;
        if (lane < 32) co_s[wv][lane] = co[(size_t)atom * 32 + lane];  // wave-private row

        float dens = ccenter[(size_t)atom * 64 + lane];
        {
            float s = 0.f;
#pragma unroll
            for (int kk = 0; kk < 8; kk++) s += co_s[wv][kk] * cc_s[kk * 64 + lane];
            dens += s * s;
        }
#pragma unroll
        for (int jj = 1; jj < 4; jj++) {
            float s = 0.f;
#pragma unroll
            for (int kk = 0; kk < 8; kk++)
                s += co_s[wv][jj * 8 + kk] * cc_s[512 + kk * 64 + lane];
            dens += s * s;
        }
        dens_s[wv][lane] = dens;   // wave-private row

        float h = b1_s[lane];
        const float4* dp = (const float4*)dens_s[wv];
#pragma unroll
        for (int q = 0; q < 16; q++) {
            float4 dv = dp[q];
            h += dv.x * w1_s[(q * 4 + 0) * 64 + lane]
               + dv.y * w1_s[(q * 4 + 1) * 64 + lane]
               + dv.z * w1_s[(q * 4 + 2) * 64 + lane]
               + dv.w * w1_s[(q * 4 + 3) * 64 + lane];
        }
        h = ln_silu(h, g_s[lane], be_s[lane]);

        if (FINAL) {
            float s = wred_sum(h * w2t_s[lane]);
            if (lane == 0) {
                float mask = (spec[atom] >= 0) ? 1.f : 0.f;
                dst[atom] = (s + b2_s[0]) * mask;
            }
        } else {
            h_s[wv][lane] = h;     // wave-private row
            int o = lane >> 3, seg = lane & 7;
            const float4* w2p = (const float4*)(w2t_s + o * 64 + seg * 8);
            const float4* hp  = (const float4*)(&h_s[wv][seg * 8]);
            float part = dot4(w2p[0], hp[0]) + dot4(w2p[1], hp[1]);
            part += __shfl_xor(part, 1, 64);
            part += __shfl_xor(part, 2, 64);
            part += __shfl_xor(part, 4, 64);
            if (seg == 0) {
                float val = part + b2_s[o];
                if (!PASS0) val += S_in[(size_t)atom * 8 + o];
                dst[(size_t)atom * 8 + o] = val;
            }
        }
    }
}

extern "C" void kernel_launch(void* const* d_in, const int* in_sizes, int n_in,
                              void* d_out, int out_size, void* d_ws, size_t ws_size,
                              hipStream_t stream) {
    const float* cart   = (const float*)d_in[0];
    const int*   aidx   = (const int*)d_in[1];
    const int*   spec   = (const int*)d_in[2];
    const float* ccoeff = (const float*)d_in[4];
    const float* embn_W1 = (const float*)d_in[5];
    const float* embn_b1 = (const float*)d_in[6];
    const float* embn_g  = (const float*)d_in[7];
    const float* embn_be = (const float*)d_in[8];
    const float* embn_W2 = (const float*)d_in[9];
    const float* embn_b2 = (const float*)d_in[10];
    const float* embc_W1 = (const float*)d_in[11];
    const float* embc_b1 = (const float*)d_in[12];
    const float* embc_g  = (const float*)d_in[13];
    const float* embc_be = (const float*)d_in[14];
    const float* embc_W2 = (const float*)d_in[15];
    const float* embc_b2 = (const float*)d_in[16];
    const float* oc_W1 = (const float*)d_in[17];
    const float* oc_b1 = (const float*)d_in[18];
    const float* oc_g  = (const float*)d_in[19];
    const float* oc_be = (const float*)d_in[20];
    const float* oc_W2 = (const float*)d_in[21];
    const float* oc_b2 = (const float*)d_in[22];
    const float* out_W1 = (const float*)d_in[23];
    const float* out_b1 = (const float*)d_in[24];
    const float* out_g  = (const float*)d_in[25];
    const float* out_be = (const float*)d_in[26];
    const float* out_W2 = (const float*)d_in[27];
    const float* out_b2 = (const float*)d_in[28];

    float* outp = (float*)d_out;

    char* ws = (char*)d_ws;
    size_t off = 0;
    auto carve = [&](size_t bytes) { size_t o = off; off = (off + bytes + 255) & ~(size_t)255; return o; };
    ushort_t* ang16 = (ushort_t*)(ws + carve((size_t)4 * NPADC * 2));
    ushort_t* rad16 = (ushort_t*)(ws + carve((size_t)8 * NPADC * 2));
    int*   keyv    = (int*)(ws + carve((size_t)NPADC * 4));
    int*   neigh   = (int*)(ws + carve((size_t)NPADC * 4));
    int*   plist   = (int*)(ws + carve((size_t)NPADC * 4));
    float* ccenter = (float*)(ws + carve((size_t)NATOMS * 64 * 4));
    float* co0     = (float*)(ws + carve((size_t)NATOMS * 32 * 4));
    float* cocur   = (float*)(ws + carve((size_t)NATOMS * 32 * 4));
    float* Sa      = (float*)(ws + carve((size_t)NATOMS * 8 * 4));
    float* Sb      = (float*)(ws + carve((size_t)NATOMS * 8 * 4));
    float* table   = (float*)(ws + carve((size_t)TBLN * 24 * 4));
    int*   cnt     = (int*)(ws + carve((size_t)NATOMS * 4));
    int*   offs    = (int*)(ws + carve((size_t)(NATOMS + 1) * 4));
    int*   cursor  = (int*)(ws + carve((size_t)NATOMS * 4));

    hipMemsetAsync(cnt, 0, (size_t)NATOMS * 4, stream);
    k_hist<<<NPAIRS / 256, 256, 0, stream>>>(aidx, cart, cnt, plist, outp);
    k_scan<<<1, 1024, 0, stream>>>(cnt, offs, cursor);
    k_scatter<<<NPAIRS / 256, 256, 0, stream>>>(aidx, cursor, plist);

    k_emb<<<CBLK + TBLK, 256, 0, stream>>>(spec,
                                           embc_W1, embc_b1, embc_g, embc_be, embc_W2, embc_b2,
                                           ccenter,
                                           embn_W1, embn_b1, embn_g, embn_be, embn_W2, embn_b2,
                                           table);

    k_pair2<<<NPADC / 512, 256, 0, stream>>>(cart, aidx, spec, table, plist, offs + NATOMS,
                                             ang16, rad16, keyv, neigh);

    // pass 0
    k_co<true><<<NATOMS / 8, 256, 0, stream>>>(offs, ang16, rad16, keyv, table, neigh,
                                               nullptr, nullptr, co0);
    k_mlp<true, false><<<NATOMS / AMLP, 256, 0, stream>>>(
        co0, ccenter, ccoeff + 0 * 1024, oc_W1 + 0 * 4096, oc_b1 + 0 * 64,
        oc_g + 0 * 64, oc_be + 0 * 64, oc_W2 + 0 * 512, oc_b2 + 0 * 8,
        nullptr, spec, Sa);
    // pass 1
    k_co<false><<<NATOMS / 8, 256, 0, stream>>>(offs, ang16, rad16, keyv, table, neigh,
                                                Sa, co0, cocur);
    k_mlp<false, false><<<NATOMS / AMLP, 256, 0, stream>>>(
        cocur, ccenter, ccoeff + 1 * 1024, oc_W1 + 1 * 4096, oc_b1 + 1 * 64,
        oc_g + 1 * 64, oc_be + 1 * 64, oc_W2 + 1 * 512, oc_b2 + 1 * 8,
        Sa, spec, Sb);
    // pass 2
    k_co<false><<<NATOMS / 8, 256, 0, stream>>>(offs, ang16, rad16, keyv, table, neigh,
                                                Sb, co0, cocur);
    k_mlp<false, false><<<NATOMS / AMLP, 256, 0, stream>>>(
        cocur, ccenter, ccoeff + 2 * 1024, oc_W1 + 2 * 4096, oc_b1 + 2 * 64,
        oc_g + 2 * 64, oc_be + 2 * 64, oc_W2 + 2 * 512, oc_b2 + 2 * 8,
        Sb, spec, Sa);
    // final
    k_co<false><<<NATOMS / 8, 256, 0, stream>>>(offs, ang16, rad16, keyv, table, neigh,
                                                Sa, co0, cocur);
    k_mlp<false, true><<<NATOMS / AMLP, 256, 0, stream>>>(
        cocur, ccenter, ccoeff + 3 * 1024, out_W1, out_b1, out_g, out_be,
        out_W2, out_b2, Sa, spec, outp + (size_t)NPAIRS * 3);
}

// Round 13
// 238.568 us; speedup vs baseline: 2.0102x; 1.0240x over previous
//
#include <hip/hip_runtime.h>
#include <math.h>

#define NWAVE   8
#define NATOMS  16384
#define NPAIRS  524288
#define NSPEC   117
#define TBLN    (NSPEC * NSPEC)
#define NPADC   (NPAIRS + NATOMS * 8)   // 655360 max padded slots
#define HBLK    (NPAIRS / 256)          // 2048 hist blocks
#define CBLK    (NATOMS / 4)            // 4096 center blocks
#define TBLK    ((TBLN + 3) / 4)        // 3423 table blocks

typedef unsigned short ushort_t;
typedef unsigned int uint_t;

// ---------- helpers ----------
__device__ __forceinline__ float wred_sum(float v) {
#pragma unroll
    for (int o = 1; o < 64; o <<= 1) v += __shfl_xor(v, o, 64);
    return v;
}

__device__ __forceinline__ float ln_silu(float h, float gg, float bb) {
    float m = wred_sum(h) * (1.f / 64.f);
    float c = h - m;
    float v = wred_sum(c * c) * (1.f / 64.f);
    float y = c * rsqrtf(v + 1e-5f) * gg + bb;
    return y / (1.f + expf(-y));
}

__device__ __forceinline__ float dot4(float4 a, float4 b) {
    return a.x * b.x + a.y * b.y + a.z * b.z + a.w * b.w;
}

__device__ __forceinline__ ushort_t f2bf(float x) {
    uint_t u = __float_as_uint(x);
    u += 0x7FFF + ((u >> 16) & 1);
    return (ushort_t)(u >> 16);
}
__device__ __forceinline__ float bf2f(ushort_t s) {
    return __uint_as_float(((uint_t)s) << 16);
}

// ---------- k_front: hist (blocks [0,HBLK)) + center MLP + table MLP ----------
__global__ void k_front(const int* __restrict__ aidx, const float* __restrict__ cart,
                        int* __restrict__ cnt, int* __restrict__ plist,
                        float* __restrict__ dist_out,
                        const int* __restrict__ spec,
                        const float* __restrict__ cW1, const float* __restrict__ cb1,
                        const float* __restrict__ cg,  const float* __restrict__ cbe,
                        const float* __restrict__ cW2, const float* __restrict__ cb2,
                        float* __restrict__ ccoef,
                        const float* __restrict__ nW1, const float* __restrict__ nb1,
                        const float* __restrict__ ng,  const float* __restrict__ nbe,
                        const float* __restrict__ nW2, const float* __restrict__ nb2,
                        float* __restrict__ table) {
    __shared__ float h_s[4][64];
    int lane = threadIdx.x & 63, slot = threadIdx.x >> 6;
    if (blockIdx.x < HBLK) {
        int p = blockIdx.x * 256 + threadIdx.x;
        atomicAdd(&cnt[aidx[p]], 1);
        int i0 = aidx[p];
        int i1 = aidx[NPAIRS + p];
        float dv0 = cart[i0 * 3 + 0] - cart[i1 * 3 + 0];
        float dv1 = cart[i0 * 3 + 1] - cart[i1 * 3 + 1];
        float dv2 = cart[i0 * 3 + 2] - cart[i1 * 3 + 2];
        dist_out[(size_t)p * 3 + 0] = dv0;
        dist_out[(size_t)p * 3 + 1] = dv1;
        dist_out[(size_t)p * 3 + 2] = dv2;
        for (int q = p; q < NPADC; q += NPAIRS) plist[q] = -1;
    } else if (blockIdx.x < HBLK + CBLK) {
        int atom = (blockIdx.x - HBLK) * 4 + slot;
        int s = spec[atom] + 1;
        float h = cW1[s * 64 + lane] + cb1[lane];
        h = ln_silu(h, cg[lane], cbe[lane]);
        h_s[slot][lane] = h;
        __syncthreads();
        float o = cb2[lane];
#pragma unroll 8
        for (int i = 0; i < 64; i++) o += h_s[slot][i] * cW2[i * 64 + lane];
        ccoef[atom * 64 + lane] = o;
    } else {
        int key = (blockIdx.x - HBLK - CBLK) * 4 + slot;
        int kk = (key < TBLN) ? key : 0;
        int s0 = kk / NSPEC + 1, s1 = kk % NSPEC + 1;
        float h = nW1[s0 * 64 + lane] + nW1[s1 * 64 + lane] + nb1[lane];
        h = ln_silu(h, ng[lane], nbe[lane]);
        h_s[slot][lane] = h;
        __syncthreads();
        if (lane < 24 && key < TBLN) {
            float o = nb2[lane];
#pragma unroll 8
            for (int i = 0; i < 64; i++) o += h_s[slot][i] * nW2[i * 24 + lane];
            table[key * 24 + lane] = o;
        }
    }
}

__global__ void k_scan(const int* __restrict__ cnt, int* __restrict__ offs,
                       int* __restrict__ cursor) {
    __shared__ int sums[1024];
    int t = threadIdx.x;
    int base = t * 16;
    int v[16];
    int s = 0;
#pragma unroll
    for (int u = 0; u < 16; u++) { v[u] = (cnt[base + u] + 7) & ~7; s += v[u]; }
    sums[t] = s;
    __syncthreads();
    for (int d = 1; d < 1024; d <<= 1) {
        int x = (t >= d) ? sums[t - d] : 0;
        __syncthreads();
        sums[t] += x;
        __syncthreads();
    }
    int run = (t == 0) ? 0 : sums[t - 1];
#pragma unroll
    for (int u = 0; u < 16; u++) {
        offs[base + u] = run;
        cursor[base + u] = run;
        run += v[u];
    }
    if (t == 1023) offs[NATOMS] = run;
}

__global__ void k_scatter(const int* __restrict__ ai0, int* __restrict__ cursor,
                          int* __restrict__ plist) {
    int p = blockIdx.x * 256 + threadIdx.x;
    if (p < NPAIRS) {
        int pos = atomicAdd(&cursor[ai0[p]], 1);
        plist[pos] = p;
    }
}

// ---------- per-pair: planar bf16 streams, 2 pairs/thread ----------
__global__ void k_pair2(const float* __restrict__ cart, const int* __restrict__ aidx,
                        const int* __restrict__ spec,  const float* __restrict__ table,
                        const int* __restrict__ plist, const int* __restrict__ total_p,
                        ushort_t* __restrict__ ang16,  ushort_t* __restrict__ rad16,
                        int* __restrict__ keyv,        int* __restrict__ neigh) {
    int pos0 = (blockIdx.x * 256 + threadIdx.x) * 2;
    if (pos0 >= total_p[0]) return;   // total is a multiple of 8, so pos0+1 also valid
    int2 pp = *(const int2*)(plist + pos0);

    float angv[2][4];
    float radv[2][8];
    int keys[2], neis[2];
#pragma unroll
    for (int s = 0; s < 2; s++) {
        int p = s ? pp.y : pp.x;
        if (p < 0) {
#pragma unroll
            for (int j = 0; j < 4; j++) angv[s][j] = 0.f;
#pragma unroll
            for (int k = 0; k < 8; k++) radv[s][k] = 0.f;
            keys[s] = 0; neis[s] = 0;
            continue;
        }
        int i0 = aidx[p];
        int i1 = aidx[NPAIRS + p];
        float dv0 = cart[i0 * 3 + 0] - cart[i1 * 3 + 0];
        float dv1 = cart[i0 * 3 + 1] - cart[i1 * 3 + 1];
        float dv2 = cart[i0 * 3 + 2] - cart[i1 * 3 + 2];
        float d = sqrtf(dv0 * dv0 + dv1 * dv1 + dv2 * dv2);

        int key = spec[i0] * NSPEC + spec[i1];
        const float4* ne = (const float4*)(table + (size_t)key * 24);
        float4 al_a = ne[2], al_b = ne[3];
        float4 mu_a = ne[4], mu_b = ne[5];

        float cth = cosf(d * (float)(M_PI / 4.0));
        float t0 = 0.5f * cth + 0.5f;
        float fc = t0 * t0;
        angv[s][0] = fc; angv[s][1] = dv0 * fc; angv[s][2] = dv1 * fc; angv[s][3] = dv2 * fc;

        float t;
        t = al_a.x * (d - mu_a.x); radv[s][0] = expf(-t * t);
        t = al_a.y * (d - mu_a.y); radv[s][1] = expf(-t * t);
        t = al_a.z * (d - mu_a.z); radv[s][2] = expf(-t * t);
        t = al_a.w * (d - mu_a.w); radv[s][3] = expf(-t * t);
        t = al_b.x * (d - mu_b.x); radv[s][4] = expf(-t * t);
        t = al_b.y * (d - mu_b.y); radv[s][5] = expf(-t * t);
        t = al_b.z * (d - mu_b.z); radv[s][6] = expf(-t * t);
        t = al_b.w * (d - mu_b.w); radv[s][7] = expf(-t * t);
        keys[s] = key; neis[s] = i1;
    }
#pragma unroll
    for (int j = 0; j < 4; j++) {
        uint_t v = (uint_t)f2bf(angv[0][j]) | ((uint_t)f2bf(angv[1][j]) << 16);
        *(uint_t*)(ang16 + (size_t)j * NPADC + pos0) = v;
    }
#pragma unroll
    for (int k = 0; k < 8; k++) {
        uint_t v = (uint_t)f2bf(radv[0][k]) | ((uint_t)f2bf(radv[1][k]) << 16);
        *(uint_t*)(rad16 + (size_t)k * NPADC + pos0) = v;
    }
    *(int2*)(keyv + pos0) = make_int2(keys[0], keys[1]);
    *(int2*)(neigh + pos0) = make_int2(neis[0], neis[1]);
}

// ---------- merged pass: R10 gather + contraction + MLP, 8 atoms/block ----------
// NOTE: plain __launch_bounds__(256) — NO waves/EU cap. R11's regression was the
// (256,6) VGPR cap forcing spill (VGPR_Count=40, 130MB scratch WRITE per pass).
template <bool PASS0, bool FINAL>
__global__ __launch_bounds__(256)
void k_pass(const int* __restrict__ offs,
            const ushort_t* __restrict__ ang16, const ushort_t* __restrict__ rad16,
            const int* __restrict__ keyv,  const float* __restrict__ table,
            const int* __restrict__ neigh, const float* __restrict__ S_in,
            float* __restrict__ co0,       const float* __restrict__ ccenter,
            const float* __restrict__ cc_g,
            const float* __restrict__ W1,  const float* __restrict__ b1,
            const float* __restrict__ g,   const float* __restrict__ be,
            const float* __restrict__ W2,  const float* __restrict__ b2,
            const int* __restrict__ spec,  float* __restrict__ dst) {
    __shared__ float w1_s[4096];     // raw [i][o]
    __shared__ float cc_s[1024];     // raw [row][k][m]
    __shared__ float w2t_s[512];     // [o][i] (oc); first 64 = W2 vec (final)
    __shared__ float b1_s[64], g_s[64], be_s[64], b2_s[8];
    __shared__ float co_s[8][32];
    __shared__ float dens_s[4][64], h_s[4][64];

    const int t = threadIdx.x, lane = t & 63, wv = t >> 6;
    const int abase = blockIdx.x * 8;

    // ---- stage weights (L2-hot across 2048 blocks) ----
    for (int i = t; i < 1024; i += 256) ((float4*)w1_s)[i] = ((const float4*)W1)[i];
    if (t < 256) ((float4*)cc_s)[t] = ((const float4*)cc_g)[t];
    if (FINAL) {
        if (t < 64) w2t_s[t] = W2[t];
        if (t == 64) b2_s[0] = b2[0];
    } else {
        if (t < 256) {  // transpose W2 (64x8) -> w2t (8x64)
            int i = t >> 2, o0 = (t & 3) * 2;
            w2t_s[(o0 + 0) * 64 + i] = W2[i * 8 + o0 + 0];
            w2t_s[(o0 + 1) * 64 + i] = W2[i * 8 + o0 + 1];
        }
        if (t >= 256 - 8) b2_s[t - 248] = b2[t - 248];
    }
    if (t < 64) { b1_s[t] = b1[t]; g_s[t] = g[t]; be_s[t] = be[t]; }

    // ---- gather (R10 shape): half-wave per atom ----
    {
        int la = wv * 2 + (lane >> 5);            // 0..7
        int atom = abase + la;
        int start = offs[atom], end = offs[atom + 1];
        int jk = lane & 31, j = jk >> 3, k = jk & 7;
        const ushort_t* aj = ang16 + (size_t)j * NPADC + start;
        const ushort_t* rk = rad16 + (size_t)k * NPADC + start;
        float acc = 0.f;
        if (PASS0) {
            const int* kb = keyv + start;
            for (int q = 0; q < end - start; q += 8) {
                ushort4 a0 = *(const ushort4*)(aj + q), a1 = *(const ushort4*)(aj + q + 4);
                ushort4 r0 = *(const ushort4*)(rk + q), r1 = *(const ushort4*)(rk + q + 4);
                int4 k0 = *(const int4*)(kb + q), k1 = *(const int4*)(kb + q + 4);
                float w0 = table[(size_t)k0.x * 24 + k];
                float w1v = table[(size_t)k0.y * 24 + k];
                float w2v = table[(size_t)k0.z * 24 + k];
                float w3 = table[(size_t)k0.w * 24 + k];
                float w4 = table[(size_t)k1.x * 24 + k];
                float w5 = table[(size_t)k1.y * 24 + k];
                float w6 = table[(size_t)k1.z * 24 + k];
                float w7 = table[(size_t)k1.w * 24 + k];
                acc += bf2f(a0.x) * bf2f(r0.x) * w0 + bf2f(a0.y) * bf2f(r0.y) * w1v
                     + bf2f(a0.z) * bf2f(r0.z) * w2v + bf2f(a0.w) * bf2f(r0.w) * w3
                     + bf2f(a1.x) * bf2f(r1.x) * w4 + bf2f(a1.y) * bf2f(r1.y) * w5
                     + bf2f(a1.z) * bf2f(r1.z) * w6 + bf2f(a1.w) * bf2f(r1.w) * w7;
            }
            co0[(size_t)atom * 32 + jk] = acc;
            co_s[la][jk] = acc;
        } else {
            const int* nbp = neigh + start;
            for (int q = 0; q < end - start; q += 8) {
                ushort4 a0 = *(const ushort4*)(aj + q), a1 = *(const ushort4*)(aj + q + 4);
                ushort4 r0 = *(const ushort4*)(rk + q), r1 = *(const ushort4*)(rk + q + 4);
                int4 n0 = *(const int4*)(nbp + q), n1 = *(const int4*)(nbp + q + 4);
                float w0 = S_in[(size_t)n0.x * 8 + k];
                float w1v = S_in[(size_t)n0.y * 8 + k];
                float w2v = S_in[(size_t)n0.z * 8 + k];
                float w3 = S_in[(size_t)n0.w * 8 + k];
                float w4 = S_in[(size_t)n1.x * 8 + k];
                float w5 = S_in[(size_t)n1.y * 8 + k];
                float w6 = S_in[(size_t)n1.z * 8 + k];
                float w7 = S_in[(size_t)n1.w * 8 + k];
                acc += bf2f(a0.x) * bf2f(r0.x) * w0 + bf2f(a0.y) * bf2f(r0.y) * w1v
                     + bf2f(a0.z) * bf2f(r0.z) * w2v + bf2f(a0.w) * bf2f(r0.w) * w3
                     + bf2f(a1.x) * bf2f(r1.x) * w4 + bf2f(a1.y) * bf2f(r1.y) * w5
                     + bf2f(a1.z) * bf2f(r1.z) * w6 + bf2f(a1.w) * bf2f(r1.w) * w7;
            }
            co_s[la][jk] = acc + co0[(size_t)atom * 32 + jk];
        }
    }
    __syncthreads();   // co_s + staged weights ready

    // ---- contraction + MLP: wave wv handles local atoms wv, wv+4 ----
#pragma unroll 1
    for (int la = wv; la < 8; la += 4) {
        int atom = abase + la;
        float dens = ccenter[(size_t)atom * 64 + lane];
        {
            float s = 0.f;
#pragma unroll
            for (int kk = 0; kk < 8; kk++) s += co_s[la][kk] * cc_s[kk * 64 + lane];
            dens += s * s;
        }
#pragma unroll
        for (int jj = 1; jj < 4; jj++) {
            float s = 0.f;
#pragma unroll
            for (int kk = 0; kk < 8; kk++)
                s += co_s[la][jj * 8 + kk] * cc_s[512 + kk * 64 + lane];
            dens += s * s;
        }
        dens_s[wv][lane] = dens;   // wave-private row

        float h = b1_s[lane];
        const float4* dp = (const float4*)dens_s[wv];
#pragma unroll
        for (int q = 0; q < 16; q++) {
            float4 dv = dp[q];
            h += dv.x * w1_s[(q * 4 + 0) * 64 + lane]
               + dv.y * w1_s[(q * 4 + 1) * 64 + lane]
               + dv.z * w1_s[(q * 4 + 2) * 64 + lane]
               + dv.w * w1_s[(q * 4 + 3) * 64 + lane];
        }
        h = ln_silu(h, g_s[lane], be_s[lane]);

        if (FINAL) {
            float s = wred_sum(h * w2t_s[lane]);
            if (lane == 0) {
                float mask = (spec[atom] >= 0) ? 1.f : 0.f;
                dst[atom] = (s + b2_s[0]) * mask;
            }
        } else {
            h_s[wv][lane] = h;     // wave-private row
            int o = lane >> 3, seg = lane & 7;
            const float4* w2p = (const float4*)(w2t_s + o * 64 + seg * 8);
            const float4* hp  = (const float4*)(&h_s[wv][seg * 8]);
            float part = dot4(w2p[0], hp[0]) + dot4(w2p[1], hp[1]);
            part += __shfl_xor(part, 1, 64);
            part += __shfl_xor(part, 2, 64);
            part += __shfl_xor(part, 4, 64);
            if (seg == 0) {
                float val = part + b2_s[o];
                if (!PASS0) val += S_in[(size_t)atom * 8 + o];
                dst[(size_t)atom * 8 + o] = val;
            }
        }
    }
}

extern "C" void kernel_launch(void* const* d_in, const int* in_sizes, int n_in,
                              void* d_out, int out_size, void* d_ws, size_t ws_size,
                              hipStream_t stream) {
    const float* cart   = (const float*)d_in[0];
    const int*   aidx   = (const int*)d_in[1];
    const int*   spec   = (const int*)d_in[2];
    const float* ccoeff = (const float*)d_in[4];
    const float* embn_W1 = (const float*)d_in[5];
    const float* embn_b1 = (const float*)d_in[6];
    const float* embn_g  = (const float*)d_in[7];
    const float* embn_be = (const float*)d_in[8];
    const float* embn_W2 = (const float*)d_in[9];
    const float* embn_b2 = (const float*)d_in[10];
    const float* embc_W1 = (const float*)d_in[11];
    const float* embc_b1 = (const float*)d_in[12];
    const float* embc_g  = (const float*)d_in[13];
    const float* embc_be = (const float*)d_in[14];
    const float* embc_W2 = (const float*)d_in[15];
    const float* embc_b2 = (const float*)d_in[16];
    const float* oc_W1 = (const float*)d_in[17];
    const float* oc_b1 = (const float*)d_in[18];
    const float* oc_g  = (const float*)d_in[19];
    const float* oc_be = (const float*)d_in[20];
    const float* oc_W2 = (const float*)d_in[21];
    const float* oc_b2 = (const float*)d_in[22];
    const float* out_W1 = (const float*)d_in[23];
    const float* out_b1 = (const float*)d_in[24];
    const float* out_g  = (const float*)d_in[25];
    const float* out_be = (const float*)d_in[26];
    const float* out_W2 = (const float*)d_in[27];
    const float* out_b2 = (const float*)d_in[28];

    float* outp = (float*)d_out;

    char* ws = (char*)d_ws;
    size_t off = 0;
    auto carve = [&](size_t bytes) { size_t o = off; off = (off + bytes + 255) & ~(size_t)255; return o; };
    ushort_t* ang16 = (ushort_t*)(ws + carve((size_t)4 * NPADC * 2));
    ushort_t* rad16 = (ushort_t*)(ws + carve((size_t)8 * NPADC * 2));
    int*   keyv    = (int*)(ws + carve((size_t)NPADC * 4));
    int*   neigh   = (int*)(ws + carve((size_t)NPADC * 4));
    int*   plist   = (int*)(ws + carve((size_t)NPADC * 4));
    float* ccenter = (float*)(ws + carve((size_t)NATOMS * 64 * 4));
    float* co0     = (float*)(ws + carve((size_t)NATOMS * 32 * 4));
    float* Sa      = (float*)(ws + carve((size_t)NATOMS * 8 * 4));
    float* Sb      = (float*)(ws + carve((size_t)NATOMS * 8 * 4));
    float* table   = (float*)(ws + carve((size_t)TBLN * 24 * 4));
    int*   cnt     = (int*)(ws + carve((size_t)NATOMS * 4));
    int*   offs    = (int*)(ws + carve((size_t)(NATOMS + 1) * 4));
    int*   cursor  = (int*)(ws + carve((size_t)NATOMS * 4));

    hipMemsetAsync(cnt, 0, (size_t)NATOMS * 4, stream);
    k_front<<<HBLK + CBLK + TBLK, 256, 0, stream>>>(
        aidx, cart, cnt, plist, outp, spec,
        embc_W1, embc_b1, embc_g, embc_be, embc_W2, embc_b2, ccenter,
        embn_W1, embn_b1, embn_g, embn_be, embn_W2, embn_b2, table);
    k_scan<<<1, 1024, 0, stream>>>(cnt, offs, cursor);
    k_scatter<<<NPAIRS / 256, 256, 0, stream>>>(aidx, cursor, plist);

    k_pair2<<<NPADC / 512, 256, 0, stream>>>(cart, aidx, spec, table, plist, offs + NATOMS,
                                             ang16, rad16, keyv, neigh);

    // pass 0: co0 + oc0 -> Sa
    k_pass<true, false><<<NATOMS / 8, 256, 0, stream>>>(
        offs, ang16, rad16, keyv, table, neigh, nullptr, co0, ccenter,
        ccoeff + 0 * 1024, oc_W1 + 0 * 4096, oc_b1 + 0 * 64, oc_g + 0 * 64,
        oc_be + 0 * 64, oc_W2 + 0 * 512, oc_b2 + 0 * 8, spec, Sa);
    // pass 1: S=Sa -> Sb (= Sa + oc1)
    k_pass<false, false><<<NATOMS / 8, 256, 0, stream>>>(
        offs, ang16, rad16, keyv, table, neigh, Sa, co0, ccenter,
        ccoeff + 1 * 1024, oc_W1 + 1 * 4096, oc_b1 + 1 * 64, oc_g + 1 * 64,
        oc_be + 1 * 64, oc_W2 + 1 * 512, oc_b2 + 1 * 8, spec, Sb);
    // pass 2: S=Sb -> Sa (= Sb + oc2)
    k_pass<false, false><<<NATOMS / 8, 256, 0, stream>>>(
        offs, ang16, rad16, keyv, table, neigh, Sb, co0, ccenter,
        ccoeff + 2 * 1024, oc_W1 + 2 * 4096, oc_b1 + 2 * 64, oc_g + 2 * 64,
        oc_be + 2 * 64, oc_W2 + 2 * 512, oc_b2 + 2 * 8, spec, Sa);
    // final: S=Sa -> output
    k_pass<false, true><<<NATOMS / 8, 256, 0, stream>>>(
        offs, ang16, rad16, keyv, table, neigh, Sa, co0, ccenter,
        ccoeff + 3 * 1024, out_W1, out_b1, out_g, out_be,
        out_W2, out_b2, spec, outp + (size_t)NPAIRS * 3);
}

// Round 14
// 184.798 us; speedup vs baseline: 2.5951x; 1.2910x over previous
//
#include <hip/hip_runtime.h>
#include <math.h>

#define NWAVE   8
#define NATOMS  16384
#define NPAIRS  524288
#define NSPEC   117
#define TBLN    (NSPEC * NSPEC)
#define CAP     128                     // fixed bucket capacity per atom
#define CTBLK   ((NSPEC + 3) / 4)       // 30 ctab blocks
#define TBLK    ((TBLN + 3) / 4)        // 3423 table blocks

typedef unsigned short ushort_t;
typedef unsigned int uint_t;

// ---------- helpers ----------
__device__ __forceinline__ float wred_sum(float v) {
#pragma unroll
    for (int o = 1; o < 64; o <<= 1) v += __shfl_xor(v, o, 64);
    return v;
}

__device__ __forceinline__ float ln_silu(float h, float gg, float bb) {
    float m = wred_sum(h) * (1.f / 64.f);
    float c = h - m;
    float v = wred_sum(c * c) * (1.f / 64.f);
    float y = c * rsqrtf(v + 1e-5f) * gg + bb;
    return y / (1.f + expf(-y));
}

__device__ __forceinline__ float dot4(float4 a, float4 b) {
    return a.x * b.x + a.y * b.y + a.z * b.z + a.w * b.w;
}

__device__ __forceinline__ ushort_t f2bf(float x) {
    uint_t u = __float_as_uint(x);
    u += 0x7FFF + ((u >> 16) & 1);
    return (ushort_t)(u >> 16);
}
__device__ __forceinline__ uint_t pack2(float a, float b) {
    return (uint_t)f2bf(a) | ((uint_t)f2bf(b) << 16);
}
__device__ __forceinline__ float bf_lo(uint_t u) { return __uint_as_float(u << 16); }
__device__ __forceinline__ float bf_hi(uint_t u) { return __uint_as_float(u & 0xffff0000u); }

// ---------- k_emb: species ctab MLP (blocks [0,CTBLK)) + pair-table MLP ----------
__global__ void k_emb(const float* __restrict__ cW1, const float* __restrict__ cb1,
                      const float* __restrict__ cg,  const float* __restrict__ cbe,
                      const float* __restrict__ cW2, const float* __restrict__ cb2,
                      float* __restrict__ ctab,
                      const float* __restrict__ nW1, const float* __restrict__ nb1,
                      const float* __restrict__ ng,  const float* __restrict__ nbe,
                      const float* __restrict__ nW2, const float* __restrict__ nb2,
                      float* __restrict__ table) {
    __shared__ float h_s[4][64];
    int lane = threadIdx.x & 63, slot = threadIdx.x >> 6;
    if (blockIdx.x < CTBLK) {
        int sp = blockIdx.x * 4 + slot;              // species value 0..116
        int spc = (sp < NSPEC) ? sp : 0;
        float h = cW1[(spc + 1) * 64 + lane] + cb1[lane];
        h = ln_silu(h, cg[lane], cbe[lane]);
        h_s[slot][lane] = h;
        __syncthreads();
        if (sp < NSPEC) {
            float o = cb2[lane];
#pragma unroll 8
            for (int i = 0; i < 64; i++) o += h_s[slot][i] * cW2[i * 64 + lane];
            ctab[sp * 64 + lane] = o;
        }
    } else {
        int key = (blockIdx.x - CTBLK) * 4 + slot;
        int kk = (key < TBLN) ? key : 0;
        int s0 = kk / NSPEC + 1, s1 = kk % NSPEC + 1;
        float h = nW1[s0 * 64 + lane] + nW1[s1 * 64 + lane] + nb1[lane];
        h = ln_silu(h, ng[lane], nbe[lane]);
        h_s[slot][lane] = h;
        __syncthreads();
        if (lane < 24 && key < TBLN) {
            float o = nb2[lane];
#pragma unroll 8
            for (int i = 0; i < 64; i++) o += h_s[slot][i] * nW2[i * 24 + lane];
            table[key * 24 + lane] = o;
        }
    }
}

// ---------- k_mega: per pair -> dist_out + 32B record into atom bucket ----------
// record (8 uints / 32 B): u0=ang01 u1=ang23 u2..u5=rad pairs u6=key u7=neigh
__global__ void k_mega(const float* __restrict__ cart, const int* __restrict__ aidx,
                       const int* __restrict__ spec,  const float* __restrict__ table,
                       int* __restrict__ cnt, float* __restrict__ dist_out,
                       uint_t* __restrict__ recs) {
    int p = blockIdx.x * 256 + threadIdx.x;
    int i0 = aidx[p];
    int i1 = aidx[NPAIRS + p];
    float dv0 = cart[i0 * 3 + 0] - cart[i1 * 3 + 0];
    float dv1 = cart[i0 * 3 + 1] - cart[i1 * 3 + 1];
    float dv2 = cart[i0 * 3 + 2] - cart[i1 * 3 + 2];
    float d = sqrtf(dv0 * dv0 + dv1 * dv1 + dv2 * dv2);
    dist_out[(size_t)p * 3 + 0] = dv0;
    dist_out[(size_t)p * 3 + 1] = dv1;
    dist_out[(size_t)p * 3 + 2] = dv2;

    int key = spec[i0] * NSPEC + spec[i1];
    const float4* ne = (const float4*)(table + (size_t)key * 24);
    float4 al_a = ne[2], al_b = ne[3];
    float4 mu_a = ne[4], mu_b = ne[5];

    float cth = cosf(d * (float)(M_PI / 4.0));
    float t0 = 0.5f * cth + 0.5f;
    float fc = t0 * t0;

    float r[8];
    float t;
    t = al_a.x * (d - mu_a.x); r[0] = expf(-t * t);
    t = al_a.y * (d - mu_a.y); r[1] = expf(-t * t);
    t = al_a.z * (d - mu_a.z); r[2] = expf(-t * t);
    t = al_a.w * (d - mu_a.w); r[3] = expf(-t * t);
    t = al_b.x * (d - mu_b.x); r[4] = expf(-t * t);
    t = al_b.y * (d - mu_b.y); r[5] = expf(-t * t);
    t = al_b.z * (d - mu_b.z); r[6] = expf(-t * t);
    t = al_b.w * (d - mu_b.w); r[7] = expf(-t * t);

    int pos = atomicAdd(&cnt[i0], 1) & (CAP - 1);   // clamp guards OOB (overflow ~impossible)
    uint_t* rec = recs + ((size_t)i0 * CAP + pos) * 8;
    uint4 lo, hi;
    lo.x = pack2(fc, dv0 * fc);
    lo.y = pack2(dv1 * fc, dv2 * fc);
    lo.z = pack2(r[0], r[1]);
    lo.w = pack2(r[2], r[3]);
    hi.x = pack2(r[4], r[5]);
    hi.y = pack2(r[6], r[7]);
    hi.z = (uint_t)key;
    hi.w = (uint_t)i1;
    *(uint4*)rec = lo;
    *(uint4*)(rec + 4) = hi;
}

// ---------- merged pass: bucket gather + contraction + MLP, 8 atoms/block ----------
// Gather lanes: h=lane&31, k=h&7, sg=h>>3; slot q loop q=sg,+4; j-reduce via shfl 8,16.
template <bool PASS0, bool FINAL>
__global__ __launch_bounds__(256)
void k_pass(const int* __restrict__ cnt, const uint_t* __restrict__ recs,
            const float* __restrict__ table, const float* __restrict__ S_in,
            float* __restrict__ co0,       const float* __restrict__ ctab,
            const int* __restrict__ spec,  const float* __restrict__ cc_g,
            const float* __restrict__ W1,  const float* __restrict__ b1,
            const float* __restrict__ g,   const float* __restrict__ be,
            const float* __restrict__ W2,  const float* __restrict__ b2,
            float* __restrict__ dst) {
    __shared__ float w1_s[4096];     // raw [i][o]
    __shared__ float cc_s[1024];     // raw [row][k][m]
    __shared__ float w2t_s[512];     // [o][i] (oc); first 64 = W2 vec (final)
    __shared__ float b1_s[64], g_s[64], be_s[64], b2_s[8];
    __shared__ float co_s[8][32];
    __shared__ float dens_s[4][64], h_s[4][64];

    const int t = threadIdx.x, lane = t & 63, wv = t >> 6;
    const int abase = blockIdx.x * 8;

    // ---- stage weights (L2-hot across 2048 blocks) ----
    for (int i = t; i < 1024; i += 256) ((float4*)w1_s)[i] = ((const float4*)W1)[i];
    if (t < 256) ((float4*)cc_s)[t] = ((const float4*)cc_g)[t];
    if (FINAL) {
        if (t < 64) w2t_s[t] = W2[t];
        if (t == 64) b2_s[0] = b2[0];
    } else {
        if (t < 256) {  // transpose W2 (64x8) -> w2t (8x64)
            int i = t >> 2, o0 = (t & 3) * 2;
            w2t_s[(o0 + 0) * 64 + i] = W2[i * 8 + o0 + 0];
            w2t_s[(o0 + 1) * 64 + i] = W2[i * 8 + o0 + 1];
        }
        if (t >= 256 - 8) b2_s[t - 248] = b2[t - 248];
    }
    if (t < 64) { b1_s[t] = b1[t]; g_s[t] = g[t]; be_s[t] = be[t]; }

    // ---- gather: half-wave per atom, lane=(sg,k) ----
    {
        int la = wv * 2 + (lane >> 5);            // 0..7
        int atom = abase + la;
        int n = cnt[atom];
        if (n > CAP) n = CAP;
        int h = lane & 31, k = h & 7, sg = h >> 3;
        const uint_t* rb = recs + (size_t)atom * CAP * 8;
        float acc0 = 0.f, acc1 = 0.f, acc2 = 0.f, acc3 = 0.f;
        for (int q = sg; q < n; q += 4) {
            const uint_t* r = rb + (size_t)q * 8;
            uint_t ang01 = r[0], ang23 = r[1];
            float rv = bf_lo((uint_t)((const ushort_t*)r)[4 + k]);
            float w;
            if (PASS0) {
                int ky = (int)r[6];
                w = table[(size_t)ky * 24 + k];
            } else {
                int nei = (int)r[7];
                w = S_in[(size_t)nei * 8 + k];
            }
            float rw = rv * w;
            acc0 += bf_lo(ang01) * rw;
            acc1 += bf_hi(ang01) * rw;
            acc2 += bf_lo(ang23) * rw;
            acc3 += bf_hi(ang23) * rw;
        }
        // reduce over slot-subgroups (lanes xor 8, 16 — stays within half-wave)
        acc0 += __shfl_xor(acc0, 8, 64);  acc1 += __shfl_xor(acc1, 8, 64);
        acc2 += __shfl_xor(acc2, 8, 64);  acc3 += __shfl_xor(acc3, 8, 64);
        acc0 += __shfl_xor(acc0, 16, 64); acc1 += __shfl_xor(acc1, 16, 64);
        acc2 += __shfl_xor(acc2, 16, 64); acc3 += __shfl_xor(acc3, 16, 64);
        float mine = (sg == 0) ? acc0 : (sg == 1) ? acc1 : (sg == 2) ? acc2 : acc3;
        if (PASS0) {
            co0[(size_t)atom * 32 + h] = mine;
            co_s[la][h] = mine;
        } else {
            co_s[la][h] = mine + co0[(size_t)atom * 32 + h];
        }
    }
    __syncthreads();   // co_s + staged weights ready

    // ---- contraction + MLP: wave wv handles local atoms wv, wv+4 ----
#pragma unroll 1
    for (int la = wv; la < 8; la += 4) {
        int atom = abase + la;
        int sp = spec[atom];
        float dens = ctab[(size_t)sp * 64 + lane];
        {
            float s = 0.f;
#pragma unroll
            for (int kk = 0; kk < 8; kk++) s += co_s[la][kk] * cc_s[kk * 64 + lane];
            dens += s * s;
        }
#pragma unroll
        for (int jj = 1; jj < 4; jj++) {
            float s = 0.f;
#pragma unroll
            for (int kk = 0; kk < 8; kk++)
                s += co_s[la][jj * 8 + kk] * cc_s[512 + kk * 64 + lane];
            dens += s * s;
        }
        dens_s[wv][lane] = dens;   // wave-private row

        float hh = b1_s[lane];
        const float4* dp = (const float4*)dens_s[wv];
#pragma unroll
        for (int q = 0; q < 16; q++) {
            float4 dv = dp[q];
            hh += dv.x * w1_s[(q * 4 + 0) * 64 + lane]
                + dv.y * w1_s[(q * 4 + 1) * 64 + lane]
                + dv.z * w1_s[(q * 4 + 2) * 64 + lane]
                + dv.w * w1_s[(q * 4 + 3) * 64 + lane];
        }
        hh = ln_silu(hh, g_s[lane], be_s[lane]);

        if (FINAL) {
            float s = wred_sum(hh * w2t_s[lane]);
            if (lane == 0) {
                float mask = (sp >= 0) ? 1.f : 0.f;
                dst[atom] = (s + b2_s[0]) * mask;
            }
        } else {
            h_s[wv][lane] = hh;    // wave-private row
            int o = lane >> 3, seg = lane & 7;
            const float4* w2p = (const float4*)(w2t_s + o * 64 + seg * 8);
            const float4* hp  = (const float4*)(&h_s[wv][seg * 8]);
            float part = dot4(w2p[0], hp[0]) + dot4(w2p[1], hp[1]);
            part += __shfl_xor(part, 1, 64);
            part += __shfl_xor(part, 2, 64);
            part += __shfl_xor(part, 4, 64);
            if (seg == 0) {
                float val = part + b2_s[o];
                if (!PASS0) val += S_in[(size_t)atom * 8 + o];
                dst[(size_t)atom * 8 + o] = val;
            }
        }
    }
}

extern "C" void kernel_launch(void* const* d_in, const int* in_sizes, int n_in,
                              void* d_out, int out_size, void* d_ws, size_t ws_size,
                              hipStream_t stream) {
    const float* cart   = (const float*)d_in[0];
    const int*   aidx   = (const int*)d_in[1];
    const int*   spec   = (const int*)d_in[2];
    const float* ccoeff = (const float*)d_in[4];
    const float* embn_W1 = (const float*)d_in[5];
    const float* embn_b1 = (const float*)d_in[6];
    const float* embn_g  = (const float*)d_in[7];
    const float* embn_be = (const float*)d_in[8];
    const float* embn_W2 = (const float*)d_in[9];
    const float* embn_b2 = (const float*)d_in[10];
    const float* embc_W1 = (const float*)d_in[11];
    const float* embc_b1 = (const float*)d_in[12];
    const float* embc_g  = (const float*)d_in[13];
    const float* embc_be = (const float*)d_in[14];
    const float* embc_W2 = (const float*)d_in[15];
    const float* embc_b2 = (const float*)d_in[16];
    const float* oc_W1 = (const float*)d_in[17];
    const float* oc_b1 = (const float*)d_in[18];
    const float* oc_g  = (const float*)d_in[19];
    const float* oc_be = (const float*)d_in[20];
    const float* oc_W2 = (const float*)d_in[21];
    const float* oc_b2 = (const float*)d_in[22];
    const float* out_W1 = (const float*)d_in[23];
    const float* out_b1 = (const float*)d_in[24];
    const float* out_g  = (const float*)d_in[25];
    const float* out_be = (const float*)d_in[26];
    const float* out_W2 = (const float*)d_in[27];
    const float* out_b2 = (const float*)d_in[28];

    float* outp = (float*)d_out;

    char* ws = (char*)d_ws;
    size_t off = 0;
    auto carve = [&](size_t bytes) { size_t o = off; off = (off + bytes + 255) & ~(size_t)255; return o; };
    uint_t* recs  = (uint_t*)(ws + carve((size_t)NATOMS * CAP * 32));   // 64 MB
    float* ctab   = (float*)(ws + carve((size_t)NSPEC * 64 * 4));
    float* table  = (float*)(ws + carve((size_t)TBLN * 24 * 4));
    float* co0    = (float*)(ws + carve((size_t)NATOMS * 32 * 4));
    float* Sa     = (float*)(ws + carve((size_t)NATOMS * 8 * 4));
    float* Sb     = (float*)(ws + carve((size_t)NATOMS * 8 * 4));
    int*   cnt    = (int*)(ws + carve((size_t)NATOMS * 4));

    hipMemsetAsync(cnt, 0, (size_t)NATOMS * 4, stream);

    k_emb<<<CTBLK + TBLK, 256, 0, stream>>>(embc_W1, embc_b1, embc_g, embc_be,
                                            embc_W2, embc_b2, ctab,
                                            embn_W1, embn_b1, embn_g, embn_be,
                                            embn_W2, embn_b2, table);

    k_mega<<<NPAIRS / 256, 256, 0, stream>>>(cart, aidx, spec, table, cnt, outp, recs);

    // pass 0: co0 + oc0 -> Sa
    k_pass<true, false><<<NATOMS / 8, 256, 0, stream>>>(
        cnt, recs, table, nullptr, co0, ctab, spec, ccoeff + 0 * 1024,
        oc_W1 + 0 * 4096, oc_b1 + 0 * 64, oc_g + 0 * 64, oc_be + 0 * 64,
        oc_W2 + 0 * 512, oc_b2 + 0 * 8, Sa);
    // pass 1: S=Sa -> Sb (= Sa + oc1)
    k_pass<false, false><<<NATOMS / 8, 256, 0, stream>>>(
        cnt, recs, table, Sa, co0, ctab, spec, ccoeff + 1 * 1024,
        oc_W1 + 1 * 4096, oc_b1 + 1 * 64, oc_g + 1 * 64, oc_be + 1 * 64,
        oc_W2 + 1 * 512, oc_b2 + 1 * 8, Sb);
    // pass 2: S=Sb -> Sa (= Sb + oc2)
    k_pass<false, false><<<NATOMS / 8, 256, 0, stream>>>(
        cnt, recs, table, Sb, co0, ctab, spec, ccoeff + 2 * 1024,
        oc_W1 + 2 * 4096, oc_b1 + 2 * 64, oc_g + 2 * 64, oc_be + 2 * 64,
        oc_W2 + 2 * 512, oc_b2 + 2 * 8, Sa);
    // final: S=Sa -> output
    k_pass<false, true><<<NATOMS / 8, 256, 0, stream>>>(
        cnt, recs, table, Sa, co0, ctab, spec, ccoeff + 3 * 1024,
        out_W1, out_b1, out_g, out_be, out_W2, out_b2,
        outp + (size_t)NPAIRS * 3);
}

// Round 15
// 175.358 us; speedup vs baseline: 2.7348x; 1.0538x over previous
//
#include <hip/hip_runtime.h>
#include <math.h>

#define NWAVE   8
#define NATOMS  16384
#define NPAIRS  524288
#define NSPEC   117
#define TBLN    (NSPEC * NSPEC)
#define CAP     128                     // fixed bucket capacity per atom
#define RECW    12                      // record width in uints (48 B)
#define CTBLK   ((NSPEC + 3) / 4)       // 30 ctab blocks
#define TBLK    ((TBLN + 3) / 4)        // 3423 table blocks

typedef unsigned short ushort_t;
typedef unsigned int uint_t;

// ---------- helpers ----------
__device__ __forceinline__ float wred_sum(float v) {
#pragma unroll
    for (int o = 1; o < 64; o <<= 1) v += __shfl_xor(v, o, 64);
    return v;
}

__device__ __forceinline__ float ln_silu(float h, float gg, float bb) {
    float m = wred_sum(h) * (1.f / 64.f);
    float c = h - m;
    float v = wred_sum(c * c) * (1.f / 64.f);
    float y = c * rsqrtf(v + 1e-5f) * gg + bb;
    return y / (1.f + expf(-y));
}

__device__ __forceinline__ float dot4(float4 a, float4 b) {
    return a.x * b.x + a.y * b.y + a.z * b.z + a.w * b.w;
}

__device__ __forceinline__ ushort_t f2bf(float x) {
    uint_t u = __float_as_uint(x);
    u += 0x7FFF + ((u >> 16) & 1);
    return (ushort_t)(u >> 16);
}
__device__ __forceinline__ uint_t pack2(float a, float b) {
    return (uint_t)f2bf(a) | ((uint_t)f2bf(b) << 16);
}
__device__ __forceinline__ float bf_lo(uint_t u) { return __uint_as_float(u << 16); }
__device__ __forceinline__ float bf_hi(uint_t u) { return __uint_as_float(u & 0xffff0000u); }
__device__ __forceinline__ float bf_at(const uint_t* r, int us) {
    return __uint_as_float(((uint_t)((const ushort_t*)r)[us]) << 16);
}

// ---------- k_emb: species ctab MLP (blocks [0,CTBLK)) + pair-table MLP ----------
__global__ void k_emb(const float* __restrict__ cW1, const float* __restrict__ cb1,
                      const float* __restrict__ cg,  const float* __restrict__ cbe,
                      const float* __restrict__ cW2, const float* __restrict__ cb2,
                      float* __restrict__ ctab,
                      const float* __restrict__ nW1, const float* __restrict__ nb1,
                      const float* __restrict__ ng,  const float* __restrict__ nbe,
                      const float* __restrict__ nW2, const float* __restrict__ nb2,
                      float* __restrict__ table) {
    __shared__ float h_s[4][64];
    int lane = threadIdx.x & 63, slot = threadIdx.x >> 6;
    if (blockIdx.x < CTBLK) {
        int sp = blockIdx.x * 4 + slot;              // species value 0..116
        int spc = (sp < NSPEC) ? sp : 0;
        float h = cW1[(spc + 1) * 64 + lane] + cb1[lane];
        h = ln_silu(h, cg[lane], cbe[lane]);
        h_s[slot][lane] = h;
        __syncthreads();
        if (sp < NSPEC) {
            float o = cb2[lane];
#pragma unroll 8
            for (int i = 0; i < 64; i++) o += h_s[slot][i] * cW2[i * 64 + lane];
            ctab[sp * 64 + lane] = o;
        }
    } else {
        int key = (blockIdx.x - CTBLK) * 4 + slot;
        int kk = (key < TBLN) ? key : 0;
        int s0 = kk / NSPEC + 1, s1 = kk % NSPEC + 1;
        float h = nW1[s0 * 64 + lane] + nW1[s1 * 64 + lane] + nb1[lane];
        h = ln_silu(h, ng[lane], nbe[lane]);
        h_s[slot][lane] = h;
        __syncthreads();
        if (lane < 24 && key < TBLN) {
            float o = nb2[lane];
#pragma unroll 8
            for (int i = 0; i < 64; i++) o += h_s[slot][i] * nW2[i * 24 + lane];
            table[key * 24 + lane] = o;
        }
    }
}

// ---------- k_mega: per pair -> dist_out + 48B record; 2 pairs/thread ----------
// record (12 uints): u0=ang01 u1=ang23 u2..u5=prod(rad*it0) u6..u9=rad u10=neigh u11=pad
// ushort idx: prod at [4..11], rad at [12..19]
__global__ void k_mega(const float* __restrict__ cart, const int* __restrict__ aidx,
                       const int* __restrict__ spec,  const float* __restrict__ table,
                       int* __restrict__ cnt, float* __restrict__ dist_out,
                       uint_t* __restrict__ recs) {
    int base = blockIdx.x * 256 + threadIdx.x;
#pragma unroll
    for (int s = 0; s < 2; s++) {
        int p = base + s * (NPAIRS / 2);
        int i0 = aidx[p];
        int i1 = aidx[NPAIRS + p];
        float dv0 = cart[i0 * 3 + 0] - cart[i1 * 3 + 0];
        float dv1 = cart[i0 * 3 + 1] - cart[i1 * 3 + 1];
        float dv2 = cart[i0 * 3 + 2] - cart[i1 * 3 + 2];
        float d = sqrtf(dv0 * dv0 + dv1 * dv1 + dv2 * dv2);
        dist_out[(size_t)p * 3 + 0] = dv0;
        dist_out[(size_t)p * 3 + 1] = dv1;
        dist_out[(size_t)p * 3 + 2] = dv2;

        int key = spec[i0] * NSPEC + spec[i1];
        const float4* ne = (const float4*)(table + (size_t)key * 24);
        float4 it_a = ne[0], it_b = ne[1];
        float4 al_a = ne[2], al_b = ne[3];
        float4 mu_a = ne[4], mu_b = ne[5];

        float cth = cosf(d * (float)(M_PI / 4.0));
        float t0 = 0.5f * cth + 0.5f;
        float fc = t0 * t0;

        float r[8], pr[8];
        float t;
        t = al_a.x * (d - mu_a.x); r[0] = expf(-t * t); pr[0] = r[0] * it_a.x;
        t = al_a.y * (d - mu_a.y); r[1] = expf(-t * t); pr[1] = r[1] * it_a.y;
        t = al_a.z * (d - mu_a.z); r[2] = expf(-t * t); pr[2] = r[2] * it_a.z;
        t = al_a.w * (d - mu_a.w); r[3] = expf(-t * t); pr[3] = r[3] * it_a.w;
        t = al_b.x * (d - mu_b.x); r[4] = expf(-t * t); pr[4] = r[4] * it_b.x;
        t = al_b.y * (d - mu_b.y); r[5] = expf(-t * t); pr[5] = r[5] * it_b.y;
        t = al_b.z * (d - mu_b.z); r[6] = expf(-t * t); pr[6] = r[6] * it_b.z;
        t = al_b.w * (d - mu_b.w); r[7] = expf(-t * t); pr[7] = r[7] * it_b.w;

        int pos = atomicAdd(&cnt[i0], 1) & (CAP - 1);
        uint_t* rec = recs + ((size_t)i0 * CAP + pos) * RECW;
        uint4 w0, w1, w2;
        w0.x = pack2(fc, dv0 * fc);
        w0.y = pack2(dv1 * fc, dv2 * fc);
        w0.z = pack2(pr[0], pr[1]);
        w0.w = pack2(pr[2], pr[3]);
        w1.x = pack2(pr[4], pr[5]);
        w1.y = pack2(pr[6], pr[7]);
        w1.z = pack2(r[0], r[1]);
        w1.w = pack2(r[2], r[3]);
        w2.x = pack2(r[4], r[5]);
        w2.y = pack2(r[6], r[7]);
        w2.z = (uint_t)i1;
        w2.w = 0u;
        *(uint4*)(rec + 0) = w0;
        *(uint4*)(rec + 4) = w1;
        *(uint4*)(rec + 8) = w2;
    }
}

// ---------- merged pass: wave-per-atom gather + contraction + MLP, 4 atoms/block ----------
template <bool PASS0, bool FINAL>
__global__ __launch_bounds__(256)
void k_pass(const int* __restrict__ cnt, const uint_t* __restrict__ recs,
            const float* __restrict__ S_in,
            float* __restrict__ co0,       const float* __restrict__ ctab,
            const int* __restrict__ spec,  const float* __restrict__ cc_g,
            const float* __restrict__ W1,  const float* __restrict__ b1,
            const float* __restrict__ g,   const float* __restrict__ be,
            const float* __restrict__ W2,  const float* __restrict__ b2,
            float* __restrict__ dst) {
    __shared__ float w1_s[4096];     // raw [i][o]
    __shared__ float cc_s[1024];     // raw [row][k][m]
    __shared__ float w2t_s[512];     // [o][i] (oc); first 64 = W2 vec (final)
    __shared__ float b1_s[64], g_s[64], be_s[64], b2_s[8];
    __shared__ float co_s[4][32];
    __shared__ float dens_s[4][64], h_s[4][64];

    const int t = threadIdx.x, lane = t & 63, wv = t >> 6;
    const int abase = blockIdx.x * 4;

    // ---- stage weights (L2-hot) ----
    for (int i = t; i < 1024; i += 256) ((float4*)w1_s)[i] = ((const float4*)W1)[i];
    if (t < 256) ((float4*)cc_s)[t] = ((const float4*)cc_g)[t];
    if (FINAL) {
        if (t < 64) w2t_s[t] = W2[t];
        if (t == 64) b2_s[0] = b2[0];
    } else {
        if (t < 256) {  // transpose W2 (64x8) -> w2t (8x64)
            int i = t >> 2, o0 = (t & 3) * 2;
            w2t_s[(o0 + 0) * 64 + i] = W2[i * 8 + o0 + 0];
            w2t_s[(o0 + 1) * 64 + i] = W2[i * 8 + o0 + 1];
        }
        if (t >= 256 - 8) b2_s[t - 248] = b2[t - 248];
    }
    if (t < 64) { b1_s[t] = b1[t]; g_s[t] = g[t]; be_s[t] = be[t]; }

    // ---- gather: one wave per atom, lanes = (sg 0..7) x (k 0..7) ----
    {
        int atom = abase + wv;
        int n = cnt[atom];
        if (n > CAP) n = CAP;
        int k = lane & 7, sg = lane >> 3;
        const uint_t* rb = recs + (size_t)atom * CAP * RECW;
        float acc0 = 0.f, acc1 = 0.f, acc2 = 0.f, acc3 = 0.f;
        for (int q = sg; q < n; q += 8) {
            const uint_t* r = rb + (size_t)q * RECW;
            uint_t ang01 = r[0], ang23 = r[1];
            float rw;
            if (PASS0) {
                rw = bf_at(r, 4 + k);                 // prod = rad*it0
            } else {
                float rv = bf_at(r, 12 + k);          // rad
                int nei = (int)r[10];
                rw = rv * S_in[(size_t)nei * 8 + k];
            }
            acc0 += bf_lo(ang01) * rw;
            acc1 += bf_hi(ang01) * rw;
            acc2 += bf_lo(ang23) * rw;
            acc3 += bf_hi(ang23) * rw;
        }
        // reduce over the 8 slot-subgroups (same k across sg)
#pragma unroll
        for (int o = 8; o < 64; o <<= 1) {
            acc0 += __shfl_xor(acc0, o, 64);
            acc1 += __shfl_xor(acc1, o, 64);
            acc2 += __shfl_xor(acc2, o, 64);
            acc3 += __shfl_xor(acc3, o, 64);
        }
        if (lane < 32) {
            int j = lane >> 3;
            float mine = (j == 0) ? acc0 : (j == 1) ? acc1 : (j == 2) ? acc2 : acc3;
            if (PASS0) {
                co0[(size_t)atom * 32 + lane] = mine;
                co_s[wv][lane] = mine;
            } else {
                co_s[wv][lane] = mine + co0[(size_t)atom * 32 + lane];
            }
        }
    }
    __syncthreads();   // co_s + staged weights ready (wave-private rows after this)

    // ---- contraction + MLP: wave wv handles atom abase+wv ----
    {
        int atom = abase + wv;
        int sp = spec[atom];
        float dens = ctab[(size_t)sp * 64 + lane];
        {
            float s = 0.f;
#pragma unroll
            for (int kk = 0; kk < 8; kk++) s += co_s[wv][kk] * cc_s[kk * 64 + lane];
            dens += s * s;
        }
#pragma unroll
        for (int jj = 1; jj < 4; jj++) {
            float s = 0.f;
#pragma unroll
            for (int kk = 0; kk < 8; kk++)
                s += co_s[wv][jj * 8 + kk] * cc_s[512 + kk * 64 + lane];
            dens += s * s;
        }
        dens_s[wv][lane] = dens;   // wave-private row

        float hh = b1_s[lane];
        const float4* dp = (const float4*)dens_s[wv];
#pragma unroll
        for (int q = 0; q < 16; q++) {
            float4 dv = dp[q];
            hh += dv.x * w1_s[(q * 4 + 0) * 64 + lane]
                + dv.y * w1_s[(q * 4 + 1) * 64 + lane]
                + dv.z * w1_s[(q * 4 + 2) * 64 + lane]
                + dv.w * w1_s[(q * 4 + 3) * 64 + lane];
        }
        hh = ln_silu(hh, g_s[lane], be_s[lane]);

        if (FINAL) {
            float s = wred_sum(hh * w2t_s[lane]);
            if (lane == 0) {
                float mask = (sp >= 0) ? 1.f : 0.f;
                dst[atom] = (s + b2_s[0]) * mask;
            }
        } else {
            h_s[wv][lane] = hh;    // wave-private row
            int o = lane >> 3, seg = lane & 7;
            const float4* w2p = (const float4*)(w2t_s + o * 64 + seg * 8);
            const float4* hp  = (const float4*)(&h_s[wv][seg * 8]);
            float part = dot4(w2p[0], hp[0]) + dot4(w2p[1], hp[1]);
            part += __shfl_xor(part, 1, 64);
            part += __shfl_xor(part, 2, 64);
            part += __shfl_xor(part, 4, 64);
            if (seg == 0) {
                float val = part + b2_s[o];
                if (!PASS0) val += S_in[(size_t)atom * 8 + o];
                dst[(size_t)atom * 8 + o] = val;
            }
        }
    }
}

extern "C" void kernel_launch(void* const* d_in, const int* in_sizes, int n_in,
                              void* d_out, int out_size, void* d_ws, size_t ws_size,
                              hipStream_t stream) {
    const float* cart   = (const float*)d_in[0];
    const int*   aidx   = (const int*)d_in[1];
    const int*   spec   = (const int*)d_in[2];
    const float* ccoeff = (const float*)d_in[4];
    const float* embn_W1 = (const float*)d_in[5];
    const float* embn_b1 = (const float*)d_in[6];
    const float* embn_g  = (const float*)d_in[7];
    const float* embn_be = (const float*)d_in[8];
    const float* embn_W2 = (const float*)d_in[9];
    const float* embn_b2 = (const float*)d_in[10];
    const float* embc_W1 = (const float*)d_in[11];
    const float* embc_b1 = (const float*)d_in[12];
    const float* embc_g  = (const float*)d_in[13];
    const float* embc_be = (const float*)d_in[14];
    const float* embc_W2 = (const float*)d_in[15];
    const float* embc_b2 = (const float*)d_in[16];
    const float* oc_W1 = (const float*)d_in[17];
    const float* oc_b1 = (const float*)d_in[18];
    const float* oc_g  = (const float*)d_in[19];
    const float* oc_be = (const float*)d_in[20];
    const float* oc_W2 = (const float*)d_in[21];
    const float* oc_b2 = (const float*)d_in[22];
    const float* out_W1 = (const float*)d_in[23];
    const float* out_b1 = (const float*)d_in[24];
    const float* out_g  = (const float*)d_in[25];
    const float* out_be = (const float*)d_in[26];
    const float* out_W2 = (const float*)d_in[27];
    const float* out_b2 = (const float*)d_in[28];

    float* outp = (float*)d_out;

    char* ws = (char*)d_ws;
    size_t off = 0;
    auto carve = [&](size_t bytes) { size_t o = off; off = (off + bytes + 255) & ~(size_t)255; return o; };
    uint_t* recs  = (uint_t*)(ws + carve((size_t)NATOMS * CAP * RECW * 4));  // 96 MB
    float* ctab   = (float*)(ws + carve((size_t)NSPEC * 64 * 4));
    float* table  = (float*)(ws + carve((size_t)TBLN * 24 * 4));
    float* co0    = (float*)(ws + carve((size_t)NATOMS * 32 * 4));
    float* Sa     = (float*)(ws + carve((size_t)NATOMS * 8 * 4));
    float* Sb     = (float*)(ws + carve((size_t)NATOMS * 8 * 4));
    int*   cnt    = (int*)(ws + carve((size_t)NATOMS * 4));

    hipMemsetAsync(cnt, 0, (size_t)NATOMS * 4, stream);

    k_emb<<<CTBLK + TBLK, 256, 0, stream>>>(embc_W1, embc_b1, embc_g, embc_be,
                                            embc_W2, embc_b2, ctab,
                                            embn_W1, embn_b1, embn_g, embn_be,
                                            embn_W2, embn_b2, table);

    k_mega<<<NPAIRS / 512, 256, 0, stream>>>(cart, aidx, spec, table, cnt, outp, recs);

    // pass 0: co0 + oc0 -> Sa
    k_pass<true, false><<<NATOMS / 4, 256, 0, stream>>>(
        cnt, recs, nullptr, co0, ctab, spec, ccoeff + 0 * 1024,
        oc_W1 + 0 * 4096, oc_b1 + 0 * 64, oc_g + 0 * 64, oc_be + 0 * 64,
        oc_W2 + 0 * 512, oc_b2 + 0 * 8, Sa);
    // pass 1: S=Sa -> Sb (= Sa + oc1)
    k_pass<false, false><<<NATOMS / 4, 256, 0, stream>>>(
        cnt, recs, Sa, co0, ctab, spec, ccoeff + 1 * 1024,
        oc_W1 + 1 * 4096, oc_b1 + 1 * 64, oc_g + 1 * 64, oc_be + 1 * 64,
        oc_W2 + 1 * 512, oc_b2 + 1 * 8, Sb);
    // pass 2: S=Sb -> Sa (= Sb + oc2)
    k_pass<false, false><<<NATOMS / 4, 256, 0, stream>>>(
        cnt, recs, Sb, co0, ctab, spec, ccoeff + 2 * 1024,
        oc_W1 + 2 * 4096, oc_b1 + 2 * 64, oc_g + 2 * 64, oc_be + 2 * 64,
        oc_W2 + 2 * 512, oc_b2 + 2 * 8, Sa);
    // final: S=Sa -> output
    k_pass<false, true><<<NATOMS / 4, 256, 0, stream>>>(
        cnt, recs, Sa, co0, ctab, spec, ccoeff + 3 * 1024,
        out_W1, out_b1, out_g, out_be, out_W2, out_b2,
        outp + (size_t)NPAIRS * 3);
}

// Round 16
// 153.819 us; speedup vs baseline: 3.1178x; 1.1400x over previous
//
#include <hip/hip_runtime.h>
#include <math.h>

#define NWAVE   8
#define NATOMS  16384
#define NPAIRS  524288
#define NSPEC   117
#define TBLN    (NSPEC * NSPEC)
#define CAP     128                     // fixed bucket capacity per atom
#define RECW    16                      // record width in uints (64 B, line-aligned)
#define CTBLK   ((NSPEC + 3) / 4)       // 30 ctab blocks
#define TBLK    ((TBLN + 3) / 4)        // 3423 table blocks

typedef unsigned short ushort_t;
typedef unsigned int uint_t;

// ---------- helpers ----------
__device__ __forceinline__ float wred_sum(float v) {
#pragma unroll
    for (int o = 1; o < 64; o <<= 1) v += __shfl_xor(v, o, 64);
    return v;
}

__device__ __forceinline__ float ln_silu(float h, float gg, float bb) {
    float m = wred_sum(h) * (1.f / 64.f);
    float c = h - m;
    float v = wred_sum(c * c) * (1.f / 64.f);
    float y = c * rsqrtf(v + 1e-5f) * gg + bb;
    return y / (1.f + expf(-y));
}

__device__ __forceinline__ float dot4(float4 a, float4 b) {
    return a.x * b.x + a.y * b.y + a.z * b.z + a.w * b.w;
}

__device__ __forceinline__ ushort_t f2bf(float x) {
    uint_t u = __float_as_uint(x);
    u += 0x7FFF + ((u >> 16) & 1);
    return (ushort_t)(u >> 16);
}
__device__ __forceinline__ uint_t pack2(float a, float b) {
    return (uint_t)f2bf(a) | ((uint_t)f2bf(b) << 16);
}
__device__ __forceinline__ float bf_lo(uint_t u) { return __uint_as_float(u << 16); }
__device__ __forceinline__ float bf_hi(uint_t u) { return __uint_as_float(u & 0xffff0000u); }
__device__ __forceinline__ float bf_at(const uint_t* r, int us) {
    return __uint_as_float(((uint_t)((const ushort_t*)r)[us]) << 16);
}

// ---------- k_emb: species ctab MLP (blocks [0,CTBLK)) + pair-table MLP ----------
__global__ void k_emb(const float* __restrict__ cW1, const float* __restrict__ cb1,
                      const float* __restrict__ cg,  const float* __restrict__ cbe,
                      const float* __restrict__ cW2, const float* __restrict__ cb2,
                      float* __restrict__ ctab,
                      const float* __restrict__ nW1, const float* __restrict__ nb1,
                      const float* __restrict__ ng,  const float* __restrict__ nbe,
                      const float* __restrict__ nW2, const float* __restrict__ nb2,
                      float* __restrict__ table) {
    __shared__ float h_s[4][64];
    int lane = threadIdx.x & 63, slot = threadIdx.x >> 6;
    if (blockIdx.x < CTBLK) {
        int sp = blockIdx.x * 4 + slot;              // species value 0..116
        int spc = (sp < NSPEC) ? sp : 0;
        float h = cW1[(spc + 1) * 64 + lane] + cb1[lane];
        h = ln_silu(h, cg[lane], cbe[lane]);
        h_s[slot][lane] = h;
        __syncthreads();
        if (sp < NSPEC) {
            float o = cb2[lane];
#pragma unroll 8
            for (int i = 0; i < 64; i++) o += h_s[slot][i] * cW2[i * 64 + lane];
            ctab[sp * 64 + lane] = o;
        }
    } else {
        int key = (blockIdx.x - CTBLK) * 4 + slot;
        int kk = (key < TBLN) ? key : 0;
        int s0 = kk / NSPEC + 1, s1 = kk % NSPEC + 1;
        float h = nW1[s0 * 64 + lane] + nW1[s1 * 64 + lane] + nb1[lane];
        h = ln_silu(h, ng[lane], nbe[lane]);
        h_s[slot][lane] = h;
        __syncthreads();
        if (lane < 24 && key < TBLN) {
            float o = nb2[lane];
#pragma unroll 8
            for (int i = 0; i < 64; i++) o += h_s[slot][i] * nW2[i * 24 + lane];
            table[key * 24 + lane] = o;
        }
    }
}

// ---------- k_mega: per pair -> dist_out + 64B record into atom bucket ----------
// record (16 uints / 64 B): u0=ang01 u1=ang23 u2..u5=prod(rad*it0) u6..u9=rad
//                           u10=neigh u11..u15=pad
// ushort idx: prod at [4..11], rad at [12..19]
__global__ void k_mega(const float* __restrict__ cart, const int* __restrict__ aidx,
                       const int* __restrict__ spec,  const float* __restrict__ table,
                       int* __restrict__ cnt, float* __restrict__ dist_out,
                       uint_t* __restrict__ recs) {
    int p = blockIdx.x * 256 + threadIdx.x;
    int i0 = aidx[p];
    int i1 = aidx[NPAIRS + p];
    float dv0 = cart[i0 * 3 + 0] - cart[i1 * 3 + 0];
    float dv1 = cart[i0 * 3 + 1] - cart[i1 * 3 + 1];
    float dv2 = cart[i0 * 3 + 2] - cart[i1 * 3 + 2];
    float d = sqrtf(dv0 * dv0 + dv1 * dv1 + dv2 * dv2);
    dist_out[(size_t)p * 3 + 0] = dv0;
    dist_out[(size_t)p * 3 + 1] = dv1;
    dist_out[(size_t)p * 3 + 2] = dv2;

    int key = spec[i0] * NSPEC + spec[i1];
    const float4* ne = (const float4*)(table + (size_t)key * 24);
    float4 it_a = ne[0], it_b = ne[1];
    float4 al_a = ne[2], al_b = ne[3];
    float4 mu_a = ne[4], mu_b = ne[5];

    float cth = cosf(d * (float)(M_PI / 4.0));
    float t0 = 0.5f * cth + 0.5f;
    float fc = t0 * t0;

    float r[8], pr[8];
    float t;
    t = al_a.x * (d - mu_a.x); r[0] = expf(-t * t); pr[0] = r[0] * it_a.x;
    t = al_a.y * (d - mu_a.y); r[1] = expf(-t * t); pr[1] = r[1] * it_a.y;
    t = al_a.z * (d - mu_a.z); r[2] = expf(-t * t); pr[2] = r[2] * it_a.z;
    t = al_a.w * (d - mu_a.w); r[3] = expf(-t * t); pr[3] = r[3] * it_a.w;
    t = al_b.x * (d - mu_b.x); r[4] = expf(-t * t); pr[4] = r[4] * it_b.x;
    t = al_b.y * (d - mu_b.y); r[5] = expf(-t * t); pr[5] = r[5] * it_b.y;
    t = al_b.z * (d - mu_b.z); r[6] = expf(-t * t); pr[6] = r[6] * it_b.z;
    t = al_b.w * (d - mu_b.w); r[7] = expf(-t * t); pr[7] = r[7] * it_b.w;

    int pos = atomicAdd(&cnt[i0], 1) & (CAP - 1);
    uint_t* rec = recs + ((size_t)i0 * CAP + pos) * RECW;
    uint4 w0, w1, w2, w3;
    w0.x = pack2(fc, dv0 * fc);
    w0.y = pack2(dv1 * fc, dv2 * fc);
    w0.z = pack2(pr[0], pr[1]);
    w0.w = pack2(pr[2], pr[3]);
    w1.x = pack2(pr[4], pr[5]);
    w1.y = pack2(pr[6], pr[7]);
    w1.z = pack2(r[0], r[1]);
    w1.w = pack2(r[2], r[3]);
    w2.x = pack2(r[4], r[5]);
    w2.y = pack2(r[6], r[7]);
    w2.z = (uint_t)i1;
    w2.w = 0u;
    w3 = make_uint4(0u, 0u, 0u, 0u);
    *(uint4*)(rec + 0) = w0;
    *(uint4*)(rec + 4) = w1;
    *(uint4*)(rec + 8) = w2;
    *(uint4*)(rec + 12) = w3;     // full-line write: no partial-line cost
}

// ---------- merged pass: wave-per-atom gather + contraction + MLP, 8 atoms/block ----------
template <bool PASS0, bool FINAL>
__global__ __launch_bounds__(512)
void k_pass(const int* __restrict__ cnt, const uint_t* __restrict__ recs,
            const float* __restrict__ S_in,
            float* __restrict__ co0,       const float* __restrict__ ctab,
            const int* __restrict__ spec,  const float* __restrict__ cc_g,
            const float* __restrict__ W1,  const float* __restrict__ b1,
            const float* __restrict__ g,   const float* __restrict__ be,
            const float* __restrict__ W2,  const float* __restrict__ b2,
            float* __restrict__ dst) {
    __shared__ float w1_s[4096];     // raw [i][o]
    __shared__ float cc_s[1024];     // raw [row][k][m]
    __shared__ float w2t_s[512];     // [o][i] (oc); first 64 = W2 vec (final)
    __shared__ float b1_s[64], g_s[64], be_s[64], b2_s[8];
    __shared__ float co_s[8][32];
    __shared__ float dens_s[8][64], h_s[8][64];

    const int t = threadIdx.x, lane = t & 63, wv = t >> 6;   // wv in [0,8)
    const int abase = blockIdx.x * 8;

    // ---- stage weights (L2-hot) ----
    for (int i = t; i < 1024; i += 512) ((float4*)w1_s)[i] = ((const float4*)W1)[i];
    if (t < 256) ((float4*)cc_s)[t] = ((const float4*)cc_g)[t];
    if (FINAL) {
        if (t < 64) w2t_s[t] = W2[t];
        if (t == 64) b2_s[0] = b2[0];
    } else {
        if (t < 256) {  // transpose W2 (64x8) -> w2t (8x64)
            int i = t >> 2, o0 = (t & 3) * 2;
            w2t_s[(o0 + 0) * 64 + i] = W2[i * 8 + o0 + 0];
            w2t_s[(o0 + 1) * 64 + i] = W2[i * 8 + o0 + 1];
        }
        if (t >= 256 && t < 264) b2_s[t - 256] = b2[t - 256];
    }
    if (t < 64) { b1_s[t] = b1[t]; g_s[t] = g[t]; be_s[t] = be[t]; }

    // ---- gather: one wave per atom, lanes = (sg 0..7) x (k 0..7) ----
    {
        int atom = abase + wv;
        int n = cnt[atom];
        if (n > CAP) n = CAP;
        int k = lane & 7, sg = lane >> 3;
        const uint_t* rb = recs + (size_t)atom * CAP * RECW;
        float acc0 = 0.f, acc1 = 0.f, acc2 = 0.f, acc3 = 0.f;
        for (int q = sg; q < n; q += 8) {
            const uint_t* r = rb + (size_t)q * RECW;
            uint_t ang01 = r[0], ang23 = r[1];
            float rw;
            if (PASS0) {
                rw = bf_at(r, 4 + k);                 // prod = rad*it0
            } else {
                float rv = bf_at(r, 12 + k);          // rad
                int nei = (int)r[10];
                rw = rv * S_in[(size_t)nei * 8 + k];
            }
            acc0 += bf_lo(ang01) * rw;
            acc1 += bf_hi(ang01) * rw;
            acc2 += bf_lo(ang23) * rw;
            acc3 += bf_hi(ang23) * rw;
        }
        // reduce over the 8 slot-subgroups (same k across sg)
#pragma unroll
        for (int o = 8; o < 64; o <<= 1) {
            acc0 += __shfl_xor(acc0, o, 64);
            acc1 += __shfl_xor(acc1, o, 64);
            acc2 += __shfl_xor(acc2, o, 64);
            acc3 += __shfl_xor(acc3, o, 64);
        }
        if (lane < 32) {
            int j = lane >> 3;
            float mine = (j == 0) ? acc0 : (j == 1) ? acc1 : (j == 2) ? acc2 : acc3;
            if (PASS0) {
                co0[(size_t)atom * 32 + lane] = mine;
                co_s[wv][lane] = mine;
            } else {
                co_s[wv][lane] = mine + co0[(size_t)atom * 32 + lane];
            }
        }
    }
    __syncthreads();   // co_s + staged weights ready (wave-private rows after this)

    // ---- contraction + MLP: wave wv handles atom abase+wv ----
    {
        int atom = abase + wv;
        int sp = spec[atom];
        float dens = ctab[(size_t)sp * 64 + lane];
        {
            float s = 0.f;
#pragma unroll
            for (int kk = 0; kk < 8; kk++) s += co_s[wv][kk] * cc_s[kk * 64 + lane];
            dens += s * s;
        }
#pragma unroll
        for (int jj = 1; jj < 4; jj++) {
            float s = 0.f;
#pragma unroll
            for (int kk = 0; kk < 8; kk++)
                s += co_s[wv][jj * 8 + kk] * cc_s[512 + kk * 64 + lane];
            dens += s * s;
        }
        dens_s[wv][lane] = dens;   // wave-private row

        float hh = b1_s[lane];
        const float4* dp = (const float4*)dens_s[wv];
#pragma unroll
        for (int q = 0; q < 16; q++) {
            float4 dv = dp[q];
            hh += dv.x * w1_s[(q * 4 + 0) * 64 + lane]
                + dv.y * w1_s[(q * 4 + 1) * 64 + lane]
                + dv.z * w1_s[(q * 4 + 2) * 64 + lane]
                + dv.w * w1_s[(q * 4 + 3) * 64 + lane];
        }
        hh = ln_silu(hh, g_s[lane], be_s[lane]);

        if (FINAL) {
            float s = wred_sum(hh * w2t_s[lane]);
            if (lane == 0) {
                float mask = (sp >= 0) ? 1.f : 0.f;
                dst[atom] = (s + b2_s[0]) * mask;
            }
        } else {
            h_s[wv][lane] = hh;    // wave-private row
            int o = lane >> 3, seg = lane & 7;
            const float4* w2p = (const float4*)(w2t_s + o * 64 + seg * 8);
            const float4* hp  = (const float4*)(&h_s[wv][seg * 8]);
            float part = dot4(w2p[0], hp[0]) + dot4(w2p[1], hp[1]);
            part += __shfl_xor(part, 1, 64);
            part += __shfl_xor(part, 2, 64);
            part += __shfl_xor(part, 4, 64);
            if (seg == 0) {
                float val = part + b2_s[o];
                if (!PASS0) val += S_in[(size_t)atom * 8 + o];
                dst[(size_t)atom * 8 + o] = val;
            }
        }
    }
}

extern "C" void kernel_launch(void* const* d_in, const int* in_sizes, int n_in,
                              void* d_out, int out_size, void* d_ws, size_t ws_size,
                              hipStream_t stream) {
    const float* cart   = (const float*)d_in[0];
    const int*   aidx   = (const int*)d_in[1];
    const int*   spec   = (const int*)d_in[2];
    const float* ccoeff = (const float*)d_in[4];
    const float* embn_W1 = (const float*)d_in[5];
    const float* embn_b1 = (const float*)d_in[6];
    const float* embn_g  = (const float*)d_in[7];
    const float* embn_be = (const float*)d_in[8];
    const float* embn_W2 = (const float*)d_in[9];
    const float* embn_b2 = (const float*)d_in[10];
    const float* embc_W1 = (const float*)d_in[11];
    const float* embc_b1 = (const float*)d_in[12];
    const float* embc_g  = (const float*)d_in[13];
    const float* embc_be = (const float*)d_in[14];
    const float* embc_W2 = (const float*)d_in[15];
    const float* embc_b2 = (const float*)d_in[16];
    const float* oc_W1 = (const float*)d_in[17];
    const float* oc_b1 = (const float*)d_in[18];
    const float* oc_g  = (const float*)d_in[19];
    const float* oc_be = (const float*)d_in[20];
    const float* oc_W2 = (const float*)d_in[21];
    const float* oc_b2 = (const float*)d_in[22];
    const float* out_W1 = (const float*)d_in[23];
    const float* out_b1 = (const float*)d_in[24];
    const float* out_g  = (const float*)d_in[25];
    const float* out_be = (const float*)d_in[26];
    const float* out_W2 = (const float*)d_in[27];
    const float* out_b2 = (const float*)d_in[28];

    float* outp = (float*)d_out;

    char* ws = (char*)d_ws;
    size_t off = 0;
    auto carve = [&](size_t bytes) { size_t o = off; off = (off + bytes + 255) & ~(size_t)255; return o; };
    uint_t* recs  = (uint_t*)(ws + carve((size_t)NATOMS * CAP * RECW * 4));  // 128 MB
    float* ctab   = (float*)(ws + carve((size_t)NSPEC * 64 * 4));
    float* table  = (float*)(ws + carve((size_t)TBLN * 24 * 4));
    float* co0    = (float*)(ws + carve((size_t)NATOMS * 32 * 4));
    float* Sa     = (float*)(ws + carve((size_t)NATOMS * 8 * 4));
    float* Sb     = (float*)(ws + carve((size_t)NATOMS * 8 * 4));
    int*   cnt    = (int*)(ws + carve((size_t)NATOMS * 4));

    hipMemsetAsync(cnt, 0, (size_t)NATOMS * 4, stream);

    k_emb<<<CTBLK + TBLK, 256, 0, stream>>>(embc_W1, embc_b1, embc_g, embc_be,
                                            embc_W2, embc_b2, ctab,
                                            embn_W1, embn_b1, embn_g, embn_be,
                                            embn_W2, embn_b2, table);

    k_mega<<<NPAIRS / 256, 256, 0, stream>>>(cart, aidx, spec, table, cnt, outp, recs);

    // pass 0: co0 + oc0 -> Sa
    k_pass<true, false><<<NATOMS / 8, 512, 0, stream>>>(
        cnt, recs, nullptr, co0, ctab, spec, ccoeff + 0 * 1024,
        oc_W1 + 0 * 4096, oc_b1 + 0 * 64, oc_g + 0 * 64, oc_be + 0 * 64,
        oc_W2 + 0 * 512, oc_b2 + 0 * 8, Sa);
    // pass 1: S=Sa -> Sb (= Sa + oc1)
    k_pass<false, false><<<NATOMS / 8, 512, 0, stream>>>(
        cnt, recs, Sa, co0, ctab, spec, ccoeff + 1 * 1024,
        oc_W1 + 1 * 4096, oc_b1 + 1 * 64, oc_g + 1 * 64, oc_be + 1 * 64,
        oc_W2 + 1 * 512, oc_b2 + 1 * 8, Sb);
    // pass 2: S=Sb -> Sa (= Sb + oc2)
    k_pass<false, false><<<NATOMS / 8, 512, 0, stream>>>(
        cnt, recs, Sb, co0, ctab, spec, ccoeff + 2 * 1024,
        oc_W1 + 2 * 4096, oc_b1 + 2 * 64, oc_g + 2 * 64, oc_be + 2 * 64,
        oc_W2 + 2 * 512, oc_b2 + 2 * 8, Sa);
    // final: S=Sa -> output
    k_pass<false, true><<<NATOMS / 8, 512, 0, stream>>>(
        cnt, recs, Sa, co0, ctab, spec, ccoeff + 3 * 1024,
        out_W1, out_b1, out_g, out_be, out_W2, out_b2,
        outp + (size_t)NPAIRS * 3);
}

// Round 17
// 153.233 us; speedup vs baseline: 3.1297x; 1.0038x over previous
//
#include <hip/hip_runtime.h>
#include <math.h>

#define NWAVE   8
#define NATOMS  16384
#define NPAIRS  524288
#define NSPEC   117
#define TBLN    (NSPEC * NSPEC)
#define CAP     128                     // fixed bucket capacity per atom
#define RECW    16                      // record width in uints (64 B, line-aligned)
#define TBW     16                      // packed table width in uints (64 B, line-aligned)
#define CTBLK   ((NSPEC + 3) / 4)       // 30 ctab blocks
#define TBLK    ((TBLN + 3) / 4)        // 3423 table blocks
#define DBLK    (NPAIRS / 256)          // 2048 dist blocks

typedef unsigned short ushort_t;
typedef unsigned int uint_t;

// ---------- helpers ----------
__device__ __forceinline__ float wred_sum(float v) {
#pragma unroll
    for (int o = 1; o < 64; o <<= 1) v += __shfl_xor(v, o, 64);
    return v;
}

__device__ __forceinline__ float ln_silu(float h, float gg, float bb) {
    float m = wred_sum(h) * (1.f / 64.f);
    float c = h - m;
    float v = wred_sum(c * c) * (1.f / 64.f);
    float y = c * rsqrtf(v + 1e-5f) * gg + bb;
    return y / (1.f + expf(-y));
}

__device__ __forceinline__ float dot4(float4 a, float4 b) {
    return a.x * b.x + a.y * b.y + a.z * b.z + a.w * b.w;
}

__device__ __forceinline__ ushort_t f2bf(float x) {
    uint_t u = __float_as_uint(x);
    u += 0x7FFF + ((u >> 16) & 1);
    return (ushort_t)(u >> 16);
}
__device__ __forceinline__ uint_t pack2(float a, float b) {
    return (uint_t)f2bf(a) | ((uint_t)f2bf(b) << 16);
}
__device__ __forceinline__ float bf_lo(uint_t u) { return __uint_as_float(u << 16); }
__device__ __forceinline__ float bf_hi(uint_t u) { return __uint_as_float(u & 0xffff0000u); }
__device__ __forceinline__ float bf_at(const uint_t* r, int us) {
    return __uint_as_float(((uint_t)((const ushort_t*)r)[us]) << 16);
}

// ---------- k_emb: ctab MLP | packed-table MLP | dist_vec + cnt-zero ----------
// packed table entry (16 uints / 64 B): u0..3 = it[0..7], u4..7 = alpha[0..7],
//                                       u8..11 = mu[0..7], u12..15 pad
__global__ void k_emb(const float* __restrict__ cW1, const float* __restrict__ cb1,
                      const float* __restrict__ cg,  const float* __restrict__ cbe,
                      const float* __restrict__ cW2, const float* __restrict__ cb2,
                      float* __restrict__ ctab,
                      const float* __restrict__ nW1, const float* __restrict__ nb1,
                      const float* __restrict__ ng,  const float* __restrict__ nbe,
                      const float* __restrict__ nW2, const float* __restrict__ nb2,
                      uint_t* __restrict__ tableb,
                      const int* __restrict__ aidx,  const float* __restrict__ cart,
                      float* __restrict__ dist_out,  int* __restrict__ cnt) {
    __shared__ float h_s[4][64];
    int lane = threadIdx.x & 63, slot = threadIdx.x >> 6;
    if (blockIdx.x < CTBLK) {
        int sp = blockIdx.x * 4 + slot;
        int spc = (sp < NSPEC) ? sp : 0;
        float h = cW1[(spc + 1) * 64 + lane] + cb1[lane];
        h = ln_silu(h, cg[lane], cbe[lane]);
        h_s[slot][lane] = h;
        __syncthreads();
        if (sp < NSPEC) {
            float o = cb2[lane];
#pragma unroll 8
            for (int i = 0; i < 64; i++) o += h_s[slot][i] * cW2[i * 64 + lane];
            ctab[sp * 64 + lane] = o;
        }
    } else if (blockIdx.x < CTBLK + TBLK) {
        int key = (blockIdx.x - CTBLK) * 4 + slot;
        int kk = (key < TBLN) ? key : 0;
        int s0 = kk / NSPEC + 1, s1 = kk % NSPEC + 1;
        float h = nW1[s0 * 64 + lane] + nW1[s1 * 64 + lane] + nb1[lane];
        h = ln_silu(h, ng[lane], nbe[lane]);
        h_s[slot][lane] = h;
        __syncthreads();
        int l24 = (lane < 24) ? lane : 0;
        float o = nb2[l24];
#pragma unroll 8
        for (int i = 0; i < 64; i++) o += h_s[slot][i] * nW2[i * 24 + l24];
        // pack pairs of outputs to bf16; lanes 0..11 write one uint each
        float oa = __shfl(o, 2 * (lane & 15), 64);
        float ob = __shfl(o, 2 * (lane & 15) + 1, 64);
        if (lane < 12 && key < TBLN) {
            tableb[(size_t)key * TBW + lane] = pack2(oa, ob);
        }
    } else {
        int b = blockIdx.x - CTBLK - TBLK;
        int p = b * 256 + threadIdx.x;
        int i0 = aidx[p];
        int i1 = aidx[NPAIRS + p];
        float dv0 = cart[i0 * 3 + 0] - cart[i1 * 3 + 0];
        float dv1 = cart[i0 * 3 + 1] - cart[i1 * 3 + 1];
        float dv2 = cart[i0 * 3 + 2] - cart[i1 * 3 + 2];
        dist_out[(size_t)p * 3 + 0] = dv0;
        dist_out[(size_t)p * 3 + 1] = dv1;
        dist_out[(size_t)p * 3 + 2] = dv2;
        if (p < NATOMS) cnt[p] = 0;
    }
}

// ---------- k_mega: per pair -> 64B record into atom bucket ----------
// record (16 uints / 64 B): u0=ang01 u1=ang23 u2..u5=prod(rad*it0) u6..u9=rad
//                           u10=neigh u11..u15=pad
// ushort idx: prod at [4..11], rad at [12..19]
__global__ void k_mega(const float* __restrict__ cart, const int* __restrict__ aidx,
                       const int* __restrict__ spec,  const uint_t* __restrict__ tableb,
                       int* __restrict__ cnt, uint_t* __restrict__ recs) {
    int p = blockIdx.x * 256 + threadIdx.x;
    int i0 = aidx[p];
    int i1 = aidx[NPAIRS + p];
    float dv0 = cart[i0 * 3 + 0] - cart[i1 * 3 + 0];
    float dv1 = cart[i0 * 3 + 1] - cart[i1 * 3 + 1];
    float dv2 = cart[i0 * 3 + 2] - cart[i1 * 3 + 2];
    float d = sqrtf(dv0 * dv0 + dv1 * dv1 + dv2 * dv2);

    int key = spec[i0] * NSPEC + spec[i1];
    const uint4* tb = (const uint4*)(tableb + (size_t)key * TBW);
    uint4 T0 = tb[0];   // it 0..7
    uint4 T1 = tb[1];   // alpha 0..7
    uint4 T2 = tb[2];   // mu 0..7

    float cth = cosf(d * (float)(M_PI / 4.0));
    float t0 = 0.5f * cth + 0.5f;
    float fc = t0 * t0;

    float it[8], al[8], mu[8];
    it[0] = bf_lo(T0.x); it[1] = bf_hi(T0.x); it[2] = bf_lo(T0.y); it[3] = bf_hi(T0.y);
    it[4] = bf_lo(T0.z); it[5] = bf_hi(T0.z); it[6] = bf_lo(T0.w); it[7] = bf_hi(T0.w);
    al[0] = bf_lo(T1.x); al[1] = bf_hi(T1.x); al[2] = bf_lo(T1.y); al[3] = bf_hi(T1.y);
    al[4] = bf_lo(T1.z); al[5] = bf_hi(T1.z); al[6] = bf_lo(T1.w); al[7] = bf_hi(T1.w);
    mu[0] = bf_lo(T2.x); mu[1] = bf_hi(T2.x); mu[2] = bf_lo(T2.y); mu[3] = bf_hi(T2.y);
    mu[4] = bf_lo(T2.z); mu[5] = bf_hi(T2.z); mu[6] = bf_lo(T2.w); mu[7] = bf_hi(T2.w);

    float r[8], pr[8];
#pragma unroll
    for (int j = 0; j < 8; j++) {
        float t = al[j] * (d - mu[j]);
        r[j] = expf(-t * t);
        pr[j] = r[j] * it[j];
    }

    int pos = atomicAdd(&cnt[i0], 1) & (CAP - 1);
    uint_t* rec = recs + ((size_t)i0 * CAP + pos) * RECW;
    uint4 w0, w1, w2, w3;
    w0.x = pack2(fc, dv0 * fc);
    w0.y = pack2(dv1 * fc, dv2 * fc);
    w0.z = pack2(pr[0], pr[1]);
    w0.w = pack2(pr[2], pr[3]);
    w1.x = pack2(pr[4], pr[5]);
    w1.y = pack2(pr[6], pr[7]);
    w1.z = pack2(r[0], r[1]);
    w1.w = pack2(r[2], r[3]);
    w2.x = pack2(r[4], r[5]);
    w2.y = pack2(r[6], r[7]);
    w2.z = (uint_t)i1;
    w2.w = 0u;
    w3 = make_uint4(0u, 0u, 0u, 0u);
    *(uint4*)(rec + 0) = w0;
    *(uint4*)(rec + 4) = w1;
    *(uint4*)(rec + 8) = w2;
    *(uint4*)(rec + 12) = w3;     // full-line write
}

// ---------- merged pass: wave-per-atom gather + contraction + MLP, 8 atoms/block ----------
template <bool PASS0, bool FINAL>
__global__ __launch_bounds__(512)
void k_pass(const int* __restrict__ cnt, const uint_t* __restrict__ recs,
            const float* __restrict__ S_in,
            float* __restrict__ co0,       const float* __restrict__ ctab,
            const int* __restrict__ spec,  const float* __restrict__ cc_g,
            const float* __restrict__ W1,  const float* __restrict__ b1,
            const float* __restrict__ g,   const float* __restrict__ be,
            const float* __restrict__ W2,  const float* __restrict__ b2,
            float* __restrict__ dst) {
    __shared__ float w1_s[4096];     // raw [i][o]
    __shared__ float cc_s[1024];     // raw [row][k][m]
    __shared__ float w2t_s[512];     // [o][i] (oc); first 64 = W2 vec (final)
    __shared__ float b1_s[64], g_s[64], be_s[64], b2_s[8];
    __shared__ float co_s[8][32];
    __shared__ float dens_s[8][64], h_s[8][64];

    const int t = threadIdx.x, lane = t & 63, wv = t >> 6;   // wv in [0,8)
    const int abase = blockIdx.x * 8;

    // ---- stage weights (L2-hot) ----
    for (int i = t; i < 1024; i += 512) ((float4*)w1_s)[i] = ((const float4*)W1)[i];
    if (t < 256) ((float4*)cc_s)[t] = ((const float4*)cc_g)[t];
    if (FINAL) {
        if (t < 64) w2t_s[t] = W2[t];
        if (t == 64) b2_s[0] = b2[0];
    } else {
        if (t < 256) {  // transpose W2 (64x8) -> w2t (8x64)
            int i = t >> 2, o0 = (t & 3) * 2;
            w2t_s[(o0 + 0) * 64 + i] = W2[i * 8 + o0 + 0];
            w2t_s[(o0 + 1) * 64 + i] = W2[i * 8 + o0 + 1];
        }
        if (t >= 256 && t < 264) b2_s[t - 256] = b2[t - 256];
    }
    if (t < 64) { b1_s[t] = b1[t]; g_s[t] = g[t]; be_s[t] = be[t]; }

    // ---- gather: one wave per atom, lanes = (sg 0..7) x (k 0..7) ----
    {
        int atom = abase + wv;
        int n = cnt[atom];
        if (n > CAP) n = CAP;
        int k = lane & 7, sg = lane >> 3;
        const uint_t* rb = recs + (size_t)atom * CAP * RECW;
        float acc0 = 0.f, acc1 = 0.f, acc2 = 0.f, acc3 = 0.f;
        for (int q = sg; q < n; q += 8) {
            const uint_t* r = rb + (size_t)q * RECW;
            uint_t ang01 = r[0], ang23 = r[1];
            float rw;
            if (PASS0) {
                rw = bf_at(r, 4 + k);                 // prod = rad*it0
            } else {
                float rv = bf_at(r, 12 + k);          // rad
                int nei = (int)r[10];
                rw = rv * S_in[(size_t)nei * 8 + k];
            }
            acc0 += bf_lo(ang01) * rw;
            acc1 += bf_hi(ang01) * rw;
            acc2 += bf_lo(ang23) * rw;
            acc3 += bf_hi(ang23) * rw;
        }
#pragma unroll
        for (int o = 8; o < 64; o <<= 1) {
            acc0 += __shfl_xor(acc0, o, 64);
            acc1 += __shfl_xor(acc1, o, 64);
            acc2 += __shfl_xor(acc2, o, 64);
            acc3 += __shfl_xor(acc3, o, 64);
        }
        if (lane < 32) {
            int j = lane >> 3;
            float mine = (j == 0) ? acc0 : (j == 1) ? acc1 : (j == 2) ? acc2 : acc3;
            if (PASS0) {
                co0[(size_t)atom * 32 + lane] = mine;
                co_s[wv][lane] = mine;
            } else {
                co_s[wv][lane] = mine + co0[(size_t)atom * 32 + lane];
            }
        }
    }
    __syncthreads();   // co_s + staged weights ready (wave-private rows after this)

    // ---- contraction + MLP: wave wv handles atom abase+wv ----
    {
        int atom = abase + wv;
        int sp = spec[atom];
        float dens = ctab[(size_t)sp * 64 + lane];
        {
            float s = 0.f;
#pragma unroll
            for (int kk = 0; kk < 8; kk++) s += co_s[wv][kk] * cc_s[kk * 64 + lane];
            dens += s * s;
        }
#pragma unroll
        for (int jj = 1; jj < 4; jj++) {
            float s = 0.f;
#pragma unroll
            for (int kk = 0; kk < 8; kk++)
                s += co_s[wv][jj * 8 + kk] * cc_s[512 + kk * 64 + lane];
            dens += s * s;
        }
        dens_s[wv][lane] = dens;   // wave-private row

        float hh = b1_s[lane];
        const float4* dp = (const float4*)dens_s[wv];
#pragma unroll
        for (int q = 0; q < 16; q++) {
            float4 dv = dp[q];
            hh += dv.x * w1_s[(q * 4 + 0) * 64 + lane]
                + dv.y * w1_s[(q * 4 + 1) * 64 + lane]
                + dv.z * w1_s[(q * 4 + 2) * 64 + lane]
                + dv.w * w1_s[(q * 4 + 3) * 64 + lane];
        }
        hh = ln_silu(hh, g_s[lane], be_s[lane]);

        if (FINAL) {
            float s = wred_sum(hh * w2t_s[lane]);
            if (lane == 0) {
                float mask = (sp >= 0) ? 1.f : 0.f;
                dst[atom] = (s + b2_s[0]) * mask;
            }
        } else {
            h_s[wv][lane] = hh;    // wave-private row
            int o = lane >> 3, seg = lane & 7;
            const float4* w2p = (const float4*)(w2t_s + o * 64 + seg * 8);
            const float4* hp  = (const float4*)(&h_s[wv][seg * 8]);
            float part = dot4(w2p[0], hp[0]) + dot4(w2p[1], hp[1]);
            part += __shfl_xor(part, 1, 64);
            part += __shfl_xor(part, 2, 64);
            part += __shfl_xor(part, 4, 64);
            if (seg == 0) {
                float val = part + b2_s[o];
                if (!PASS0) val += S_in[(size_t)atom * 8 + o];
                dst[(size_t)atom * 8 + o] = val;
            }
        }
    }
}

extern "C" void kernel_launch(void* const* d_in, const int* in_sizes, int n_in,
                              void* d_out, int out_size, void* d_ws, size_t ws_size,
                              hipStream_t stream) {
    const float* cart   = (const float*)d_in[0];
    const int*   aidx   = (const int*)d_in[1];
    const int*   spec   = (const int*)d_in[2];
    const float* ccoeff = (const float*)d_in[4];
    const float* embn_W1 = (const float*)d_in[5];
    const float* embn_b1 = (const float*)d_in[6];
    const float* embn_g  = (const float*)d_in[7];
    const float* embn_be = (const float*)d_in[8];
    const float* embn_W2 = (const float*)d_in[9];
    const float* embn_b2 = (const float*)d_in[10];
    const float* embc_W1 = (const float*)d_in[11];
    const float* embc_b1 = (const float*)d_in[12];
    const float* embc_g  = (const float*)d_in[13];
    const float* embc_be = (const float*)d_in[14];
    const float* embc_W2 = (const float*)d_in[15];
    const float* embc_b2 = (const float*)d_in[16];
    const float* oc_W1 = (const float*)d_in[17];
    const float* oc_b1 = (const float*)d_in[18];
    const float* oc_g  = (const float*)d_in[19];
    const float* oc_be = (const float*)d_in[20];
    const float* oc_W2 = (const float*)d_in[21];
    const float* oc_b2 = (const float*)d_in[22];
    const float* out_W1 = (const float*)d_in[23];
    const float* out_b1 = (const float*)d_in[24];
    const float* out_g  = (const float*)d_in[25];
    const float* out_be = (const float*)d_in[26];
    const float* out_W2 = (const float*)d_in[27];
    const float* out_b2 = (const float*)d_in[28];

    float* outp = (float*)d_out;

    char* ws = (char*)d_ws;
    size_t off = 0;
    auto carve = [&](size_t bytes) { size_t o = off; off = (off + bytes + 255) & ~(size_t)255; return o; };
    uint_t* recs   = (uint_t*)(ws + carve((size_t)NATOMS * CAP * RECW * 4));  // 128 MB
    float* ctab    = (float*)(ws + carve((size_t)NSPEC * 64 * 4));
    uint_t* tableb = (uint_t*)(ws + carve((size_t)TBLN * TBW * 4));           // 876 KB
    float* co0     = (float*)(ws + carve((size_t)NATOMS * 32 * 4));
    float* Sa      = (float*)(ws + carve((size_t)NATOMS * 8 * 4));
    float* Sb      = (float*)(ws + carve((size_t)NATOMS * 8 * 4));
    int*   cnt     = (int*)(ws + carve((size_t)NATOMS * 4));

    k_emb<<<CTBLK + TBLK + DBLK, 256, 0, stream>>>(
        embc_W1, embc_b1, embc_g, embc_be, embc_W2, embc_b2, ctab,
        embn_W1, embn_b1, embn_g, embn_be, embn_W2, embn_b2, tableb,
        aidx, cart, outp, cnt);

    k_mega<<<NPAIRS / 256, 256, 0, stream>>>(cart, aidx, spec, tableb, cnt, recs);

    // pass 0: co0 + oc0 -> Sa
    k_pass<true, false><<<NATOMS / 8, 512, 0, stream>>>(
        cnt, recs, nullptr, co0, ctab, spec, ccoeff + 0 * 1024,
        oc_W1 + 0 * 4096, oc_b1 + 0 * 64, oc_g + 0 * 64, oc_be + 0 * 64,
        oc_W2 + 0 * 512, oc_b2 + 0 * 8, Sa);
    // pass 1: S=Sa -> Sb (= Sa + oc1)
    k_pass<false, false><<<NATOMS / 8, 512, 0, stream>>>(
        cnt, recs, Sa, co0, ctab, spec, ccoeff + 1 * 1024,
        oc_W1 + 1 * 4096, oc_b1 + 1 * 64, oc_g + 1 * 64, oc_be + 1 * 64,
        oc_W2 + 1 * 512, oc_b2 + 1 * 8, Sb);
    // pass 2: S=Sb -> Sa (= Sb + oc2)
    k_pass<false, false><<<NATOMS / 8, 512, 0, stream>>>(
        cnt, recs, Sb, co0, ctab, spec, ccoeff + 2 * 1024,
        oc_W1 + 2 * 4096, oc_b1 + 2 * 64, oc_g + 2 * 64, oc_be + 2 * 64,
        oc_W2 + 2 * 512, oc_b2 + 2 * 8, Sa);
    // final: S=Sa -> output
    k_pass<false, true><<<NATOMS / 8, 512, 0, stream>>>(
        cnt, recs, Sa, co0, ctab, spec, ccoeff + 3 * 1024,
        out_W1, out_b1, out_g, out_be, out_W2, out_b2,
        outp + (size_t)NPAIRS * 3);
}